// Round 1
// baseline (635.131 us; speedup 1.0000x reference)
//
#include <hip/hip_runtime.h>
#include <hip/hip_bf16.h>

typedef __attribute__((ext_vector_type(8))) __bf16 bf16x8;
typedef __attribute__((ext_vector_type(4))) float f32x4;
typedef __attribute__((ext_vector_type(4))) unsigned short ushort4v;

typedef unsigned short u16;

// ---------- helpers ----------
__device__ __forceinline__ u16 f2bf_bits(float f) {
    union { float f; unsigned int u; } x; x.f = f;
    unsigned int r = x.u + 0x7FFFu + ((x.u >> 16) & 1u);   // RNE
    return (u16)(r >> 16);
}

__device__ __forceinline__ void gload_lds16(const void* g, void* l) {
    __builtin_amdgcn_global_load_lds(
        (const __attribute__((address_space(1))) void*)g,
        (__attribute__((address_space(3))) void*)l, 16, 0, 0);
}

// ---------- f32 -> bf16 convert (contiguous) ----------
__global__ void cvt4(const float* __restrict__ in, u16* __restrict__ out, int n) {
    int i = (blockIdx.x * 256 + threadIdx.x) << 2;
    if (i >= n) return;
    f32x4 v = *reinterpret_cast<const f32x4*>(in + i);
    ushort4v o;
    o.x = f2bf_bits(v.x); o.y = f2bf_bits(v.y);
    o.z = f2bf_bits(v.z); o.w = f2bf_bits(v.w);
    *reinterpret_cast<ushort4v*>(out + i) = o;
}

// ---------- f32 (R x C) -> bf16 transposed (C x R) ----------
__global__ void transpose_cvt(const float* __restrict__ in, u16* __restrict__ out,
                              int R, int C) {
    __shared__ float t[32][33];
    const int c0 = blockIdx.x << 5;
    const int r0 = blockIdx.y << 5;
    const int tx = threadIdx.x;
    const int ty = threadIdx.y;
    #pragma unroll
    for (int i = ty; i < 32; i += 8)
        t[i][tx] = in[(size_t)(r0 + i) * C + c0 + tx];
    __syncthreads();
    #pragma unroll
    for (int i = ty; i < 32; i += 8)
        out[(size_t)(c0 + i) * R + r0 + tx] = f2bf_bits(t[tx][i]);
}

// ---------- reparameterization: zs = mu + exp(0.5*lv)*eps ----------
__global__ void sampler(const float* __restrict__ mu, const float* __restrict__ lv,
                        const float* __restrict__ eps, u16* __restrict__ zs, int n) {
    int i = blockIdx.x * 256 + threadIdx.x;
    if (i >= n) return;
    float v = mu[i] + __expf(0.5f * lv[i]) * eps[i];
    zs[i] = f2bf_bits(v);
}

// ---------- bf16 GEMM: C = A(MxK) * Bt(NxK)^T + bias ----------
// MODE 0: out = relu(C) as bf16 into obf (ld N)
// MODE 1: out = C as f32 into of32 (ld N)
// MODE 2: z-split: col<512 -> of32(mu, ld 512), col>=512 -> olv(logvar, ld 512)
template<int MODE>
__global__ __launch_bounds__(256)
void gemm_bt(const u16* __restrict__ A, const u16* __restrict__ Bt,
             const float* __restrict__ bias,
             u16* __restrict__ obf, float* __restrict__ of32, float* __restrict__ olv,
             int M, int N, int K)
{
    __shared__ u16 As[128 * 32];
    __shared__ u16 Bs[128 * 32];

    const int tid  = threadIdx.x;
    const int lane = tid & 63;
    const int w    = tid >> 6;          // wave 0..3
    const int wr   = w >> 1;            // wave row (0..1)
    const int wc   = w & 1;             // wave col (0..1)

    const int nbx  = N >> 7;
    const int brow = (blockIdx.x / nbx) << 7;
    const int bcol = (blockIdx.x % nbx) << 7;

    // staging: thread covers tile bytes j*4096 + w*1024 + lane*16
    const int srow = (w << 4) + (lane >> 2);        // 0..63
    const int scol = (lane & 3) << 3;               // 0,8,16,24
    const size_t aoff0 = (size_t)(brow + srow) * K + scol;
    const size_t aoff1 = (size_t)(brow + 64 + srow) * K + scol;
    const size_t boff0 = (size_t)(bcol + srow) * K + scol;
    const size_t boff1 = (size_t)(bcol + 64 + srow) * K + scol;

    u16* asl0 = &As[(w << 9)];          // wave-uniform LDS bases
    u16* asl1 = &As[2048 + (w << 9)];
    u16* bsl0 = &Bs[(w << 9)];
    u16* bsl1 = &Bs[2048 + (w << 9)];

    f32x4 acc[4][4];
    #pragma unroll
    for (int m = 0; m < 4; ++m)
        #pragma unroll
        for (int n = 0; n < 4; ++n)
            acc[m][n] = (f32x4)(0.0f);

    const int ar   = (wr << 6) + (lane & 15);
    const int br   = (wc << 6) + (lane & 15);
    const int koff = (lane >> 4) << 3;

    for (int kt = 0; kt < K; kt += 32) {
        __syncthreads();                 // previous tile reads done
        gload_lds16(A  + aoff0 + kt, asl0);
        gload_lds16(A  + aoff1 + kt, asl1);
        gload_lds16(Bt + boff0 + kt, bsl0);
        gload_lds16(Bt + boff1 + kt, bsl1);
        __syncthreads();                 // drains vmcnt before barrier

        bf16x8 av[4], bv[4];
        #pragma unroll
        for (int m = 0; m < 4; ++m)
            av[m] = *reinterpret_cast<const bf16x8*>(&As[(ar + (m << 4)) * 32 + koff]);
        #pragma unroll
        for (int n = 0; n < 4; ++n)
            bv[n] = *reinterpret_cast<const bf16x8*>(&Bs[(br + (n << 4)) * 32 + koff]);

        #pragma unroll
        for (int m = 0; m < 4; ++m)
            #pragma unroll
            for (int n = 0; n < 4; ++n)
                acc[m][n] = __builtin_amdgcn_mfma_f32_16x16x32_bf16(
                    av[m], bv[n], acc[m][n], 0, 0, 0);
    }

    // epilogue
    float bv4[4];
    #pragma unroll
    for (int n = 0; n < 4; ++n)
        bv4[n] = bias[bcol + (wc << 6) + (n << 4) + (lane & 15)];

    const int erow0 = brow + (wr << 6) + ((lane >> 4) << 2);
    const int ecol0 = bcol + (wc << 6) + (lane & 15);

    #pragma unroll
    for (int m = 0; m < 4; ++m) {
        #pragma unroll
        for (int i = 0; i < 4; ++i) {
            const int r = erow0 + (m << 4) + i;
            #pragma unroll
            for (int n = 0; n < 4; ++n) {
                const int c = ecol0 + (n << 4);
                float v = acc[m][n][i] + bv4[n];
                if (MODE == 0) {
                    v = v > 0.0f ? v : 0.0f;
                    obf[(size_t)r * N + c] = f2bf_bits(v);
                } else if (MODE == 1) {
                    of32[(size_t)r * N + c] = v;
                } else {
                    if (c < 512) of32[(size_t)r * 512 + c] = v;
                    else         olv[(size_t)r * 512 + (c - 512)] = v;
                }
            }
        }
    }
}

// ---------- launch ----------
extern "C" void kernel_launch(void* const* d_in, const int* in_sizes, int n_in,
                              void* d_out, int out_size, void* d_ws, size_t ws_size,
                              hipStream_t stream) {
    const float* x   = (const float*)d_in[0];
    const float* We1 = (const float*)d_in[1];
    const float* be1 = (const float*)d_in[2];
    const float* We2 = (const float*)d_in[3];
    const float* be2 = (const float*)d_in[4];
    const float* Wd1 = (const float*)d_in[5];
    const float* bd1 = (const float*)d_in[6];
    const float* Wd2 = (const float*)d_in[7];
    const float* bd2 = (const float*)d_in[8];
    const float* eps = (const float*)d_in[9];

    const int B = 4096, D = 4096, H = 4096, LAT = 512;

    char* ws = (char*)d_ws;
    u16* xb  = (u16*)(ws);                 // B*D bf16      (33,554,432 B)
    u16* w1t = (u16*)(ws + 33554432);      // (H x D)       (33,554,432 B)
    u16* w2t = (u16*)(ws + 67108864);      // (2LAT x H)    ( 8,388,608 B)
    u16* w3t = (u16*)(ws + 75497472);      // (H x LAT)     ( 4,194,304 B)
    u16* w4t = (u16*)(ws + 79691776);      // (D x H)       (33,554,432 B)
    u16* h   = (u16*)(ws + 113246208);     // B*H bf16      (33,554,432 B)  end=146,800,640
    u16* zs  = w1t;                        // B*LAT bf16 (aliases w1t, free after GEMM1/2)
    u16* hd  = xb;                         // B*H  bf16 (aliases xb, free after GEMM1)

    float* recon = (float*)d_out;                       // B*D
    float* mu    = recon + (size_t)B * D;               // B*LAT
    float* lv    = mu + (size_t)B * LAT;                // B*LAT

    dim3 tb(32, 8);

    // f32 -> bf16 conversions (weights transposed to N x K)
    cvt4<<<(B * D / 4 + 255) / 256, 256, 0, stream>>>(x, xb, B * D);
    transpose_cvt<<<dim3(H / 32, D / 32), tb, 0, stream>>>(We1, w1t, D, H);
    transpose_cvt<<<dim3(2 * LAT / 32, H / 32), tb, 0, stream>>>(We2, w2t, H, 2 * LAT);
    transpose_cvt<<<dim3(H / 32, LAT / 32), tb, 0, stream>>>(Wd1, w3t, LAT, H);
    transpose_cvt<<<dim3(D / 32, H / 32), tb, 0, stream>>>(Wd2, w4t, H, D);

    // h = relu(x @ We1 + be1)        M=B, N=H, K=D
    gemm_bt<0><<<(B / 128) * (H / 128), 256, 0, stream>>>(xb, w1t, be1, h, nullptr, nullptr, B, H, D);
    // z = h @ We2 + be2 -> mu, logvar  M=B, N=2LAT, K=H
    gemm_bt<2><<<(B / 128) * (2 * LAT / 128), 256, 0, stream>>>(h, w2t, be2, nullptr, mu, lv, B, 2 * LAT, H);
    // zs = mu + exp(0.5*lv)*eps
    sampler<<<(B * LAT + 255) / 256, 256, 0, stream>>>(mu, lv, eps, zs, B * LAT);
    // hd = relu(zs @ Wd1 + bd1)      M=B, N=H, K=LAT
    gemm_bt<0><<<(B / 128) * (H / 128), 256, 0, stream>>>(zs, w3t, bd1, hd, nullptr, nullptr, B, H, LAT);
    // recon = hd @ Wd2 + bd2         M=B, N=D, K=H
    gemm_bt<1><<<(B / 128) * (D / 128), 256, 0, stream>>>(hd, w4t, bd2, nullptr, recon, nullptr, B, D, H);
}

// Round 2
// 448.435 us; speedup vs baseline: 1.4163x; 1.4163x over previous
//
#include <hip/hip_runtime.h>
#include <hip/hip_bf16.h>

typedef __attribute__((ext_vector_type(8))) __bf16 bf16x8;
typedef __attribute__((ext_vector_type(4))) float f32x4;
typedef __attribute__((ext_vector_type(4))) unsigned short ushort4v;
typedef unsigned short u16;

// ---------- helpers ----------
__device__ __forceinline__ u16 f2bf_bits(float f) {
    union { float f; unsigned int u; } x; x.f = f;
    unsigned int r = x.u + 0x7FFFu + ((x.u >> 16) & 1u);   // RNE
    return (u16)(r >> 16);
}

__device__ __forceinline__ void gload_lds16(const void* g, void* l) {
    __builtin_amdgcn_global_load_lds(
        (const __attribute__((address_space(1))) void*)g,
        (__attribute__((address_space(3))) void*)l, 16, 0, 0);
}

#define BARRIER()  __builtin_amdgcn_s_barrier()
#define SCHEDB()   __builtin_amdgcn_sched_barrier(0)
#define LGKM0()    asm volatile("s_waitcnt lgkmcnt(0)" ::: "memory")
#define VMW4()     asm volatile("s_waitcnt vmcnt(4)" ::: "memory")
#define VMW0()     asm volatile("s_waitcnt vmcnt(0)" ::: "memory")

// ---------- f32 -> bf16 convert (contiguous) ----------
__global__ void cvt4(const float* __restrict__ in, u16* __restrict__ out, int n) {
    int i = (blockIdx.x * 256 + threadIdx.x) << 2;
    if (i >= n) return;
    f32x4 v = *reinterpret_cast<const f32x4*>(in + i);
    ushort4v o;
    o.x = f2bf_bits(v.x); o.y = f2bf_bits(v.y);
    o.z = f2bf_bits(v.z); o.w = f2bf_bits(v.w);
    *reinterpret_cast<ushort4v*>(out + i) = o;
}

// ---------- f32 (R x C) -> bf16 transposed (C x R) ----------
__global__ void transpose_cvt(const float* __restrict__ in, u16* __restrict__ out,
                              int R, int C) {
    __shared__ float t[32][33];
    const int c0 = blockIdx.x << 5;
    const int r0 = blockIdx.y << 5;
    const int tx = threadIdx.x;
    const int ty = threadIdx.y;
    #pragma unroll
    for (int i = ty; i < 32; i += 8)
        t[i][tx] = in[(size_t)(r0 + i) * C + c0 + tx];
    __syncthreads();
    #pragma unroll
    for (int i = ty; i < 32; i += 8)
        out[(size_t)(c0 + i) * R + r0 + tx] = f2bf_bits(t[tx][i]);
}

// ---------- reparameterization ----------
__global__ void sampler(const float* __restrict__ mu, const float* __restrict__ lv,
                        const float* __restrict__ eps, u16* __restrict__ zs, int n) {
    int i = blockIdx.x * 256 + threadIdx.x;
    if (i >= n) return;
    float v = mu[i] + __expf(0.5f * lv[i]) * eps[i];
    zs[i] = f2bf_bits(v);
}

// ---------- 128x128 2-phase GEMM (kept for N=1024 z-GEMM) ----------
// MODE 2: z-split: col<512 -> of32(mu), col>=512 -> olv(logvar)
template<int MODE>
__global__ __launch_bounds__(256)
void gemm_bt(const u16* __restrict__ A, const u16* __restrict__ Bt,
             const float* __restrict__ bias,
             u16* __restrict__ obf, float* __restrict__ of32, float* __restrict__ olv,
             int M, int N, int K)
{
    __shared__ u16 As[128 * 32];
    __shared__ u16 Bs[128 * 32];

    const int tid  = threadIdx.x;
    const int lane = tid & 63;
    const int w    = tid >> 6;
    const int wr   = w >> 1;
    const int wc   = w & 1;

    const int nbx  = N >> 7;
    const int brow = (blockIdx.x / nbx) << 7;
    const int bcol = (blockIdx.x % nbx) << 7;

    const int srow = (w << 4) + (lane >> 2);
    const int scol = (lane & 3) << 3;
    const size_t aoff0 = (size_t)(brow + srow) * K + scol;
    const size_t aoff1 = (size_t)(brow + 64 + srow) * K + scol;
    const size_t boff0 = (size_t)(bcol + srow) * K + scol;
    const size_t boff1 = (size_t)(bcol + 64 + srow) * K + scol;

    u16* asl0 = &As[(w << 9)];
    u16* asl1 = &As[2048 + (w << 9)];
    u16* bsl0 = &Bs[(w << 9)];
    u16* bsl1 = &Bs[2048 + (w << 9)];

    f32x4 acc[4][4];
    #pragma unroll
    for (int m = 0; m < 4; ++m)
        #pragma unroll
        for (int n = 0; n < 4; ++n)
            acc[m][n] = (f32x4)(0.0f);

    const int ar   = (wr << 6) + (lane & 15);
    const int br   = (wc << 6) + (lane & 15);
    const int koff = (lane >> 4) << 3;

    for (int kt = 0; kt < K; kt += 32) {
        __syncthreads();
        gload_lds16(A  + aoff0 + kt, asl0);
        gload_lds16(A  + aoff1 + kt, asl1);
        gload_lds16(Bt + boff0 + kt, bsl0);
        gload_lds16(Bt + boff1 + kt, bsl1);
        __syncthreads();

        bf16x8 av[4], bv[4];
        #pragma unroll
        for (int m = 0; m < 4; ++m)
            av[m] = *reinterpret_cast<const bf16x8*>(&As[(ar + (m << 4)) * 32 + koff]);
        #pragma unroll
        for (int n = 0; n < 4; ++n)
            bv[n] = *reinterpret_cast<const bf16x8*>(&Bs[(br + (n << 4)) * 32 + koff]);

        #pragma unroll
        for (int m = 0; m < 4; ++m)
            #pragma unroll
            for (int n = 0; n < 4; ++n)
                acc[m][n] = __builtin_amdgcn_mfma_f32_16x16x32_bf16(
                    av[m], bv[n], acc[m][n], 0, 0, 0);
    }

    float bv4[4];
    #pragma unroll
    for (int n = 0; n < 4; ++n)
        bv4[n] = bias[bcol + (wc << 6) + (n << 4) + (lane & 15)];

    const int erow0 = brow + (wr << 6) + ((lane >> 4) << 2);
    const int ecol0 = bcol + (wc << 6) + (lane & 15);

    #pragma unroll
    for (int m = 0; m < 4; ++m) {
        #pragma unroll
        for (int i = 0; i < 4; ++i) {
            const int r = erow0 + (m << 4) + i;
            #pragma unroll
            for (int n = 0; n < 4; ++n) {
                const int c = ecol0 + (n << 4);
                float v = acc[m][n][i] + bv4[n];
                if (MODE == 0) {
                    v = v > 0.0f ? v : 0.0f;
                    obf[(size_t)r * N + c] = f2bf_bits(v);
                } else if (MODE == 1) {
                    of32[(size_t)r * N + c] = v;
                } else {
                    if (c < 512) of32[(size_t)r * 512 + c] = v;
                    else         olv[(size_t)r * 512 + (c - 512)] = v;
                }
            }
        }
    }
}

// ---------- 256x256 8-phase GEMM (T2+T3+T4+T5, BK=64, 8 waves) ----------
// C = A(MxK) * Bt(NxK)^T + bias.  MODE 0: relu->bf16 obf.  MODE 1: f32 of32.
// LDS 128KiB: buf{0,1} x { A0,A1,B0,B1 } halves of 16KiB (128 rows x 64 cols bf16).
// Swizzle (involution, bits 4-6): byte ^= ((row&7)<<4); applied to pre-permuted
// global source (gload_lds writes linearly) and to ds_read addresses.
template<int MODE>
__global__ __launch_bounds__(512, 2)
void gemm256(const u16* __restrict__ A, const u16* __restrict__ Bt,
             const float* __restrict__ bias,
             u16* __restrict__ obf, float* __restrict__ of32,
             int M, int N, int K)
{
    extern __shared__ char lds[];
    const int tid  = threadIdx.x;
    const int lane = tid & 63;
    const int w    = tid >> 6;          // 0..7
    const int wr   = w >> 2;            // 0..1  (M half)
    const int wc   = w & 3;             // 0..3  (N quarter)

    // XCD-aware swizzle (grid is always a multiple of 8 here)
    int bid = blockIdx.x;
    const int cpx = gridDim.x >> 3;
    bid = (bid & 7) * cpx + (bid >> 3);
    const int nbx  = N >> 8;
    const int brow = (bid / nbx) << 8;
    const int bcol = (bid % nbx) << 8;

    // ---- staging source decode (chunk c covers LDS linear bytes c*8192 + tid*16) ----
    // linear l -> row = l>>7, col-bytes = (l&127) ^ ((row&7)<<4)
    const int srow  = tid >> 3;                                  // 0..63 (chunk0), +64 chunk1
    const int scole = (((tid & 7) ^ (srow & 7)) << 4) >> 1;      // col in elems, 8-aligned
    const size_t aoff = (size_t)(brow + srow) * K + scole;
    const size_t boff = (size_t)(bcol + srow) * K + scole;
    const size_t rowK64 = (size_t)64 * K;
    const int wave1024 = w << 10;

    // ---- read-side address components ----
    const int lo16 = (lane >> 4) << 4;          // k-chunk within slice (bits 4-5)
    const int swzm = (lane & 7) << 4;           // swizzle XOR mask (row&7 == lane&7)
    const int low0 = lo16 ^ swzm;               // kslice 0
    const int low1 = (64 | lo16) ^ swzm;        // kslice 1
    const int rA   = (lane & 15) << 7;
    const int rB   = ((((wc & 1) << 6) | (lane & 15)) << 7);
    const int regA = wr << 14;                  // + buf*65536
    const int regB = 32768 + ((wc >> 1) << 14); // + buf*65536

    bf16x8 a[4][2];
    bf16x8 b0[2][2];
    bf16x8 b1[2][2];
    f32x4 acc[8][4];
    #pragma unroll
    for (int m = 0; m < 8; ++m)
        #pragma unroll
        for (int n = 0; n < 4; ++n)
            acc[m][n] = (f32x4)(0.0f);

#define STAGE_A(buf, h, kt) do { \
    const u16* _s = A + aoff + (size_t)(h) * 128 * K + (size_t)(kt) * 64; \
    gload_lds16(_s,          lds + ((buf) << 16) + ((h) << 14) + wave1024); \
    gload_lds16(_s + rowK64, lds + ((buf) << 16) + ((h) << 14) + 8192 + wave1024); \
} while (0)

#define STAGE_B(buf, h, kt) do { \
    const u16* _s = Bt + boff + (size_t)(h) * 128 * K + (size_t)(kt) * 64; \
    gload_lds16(_s,          lds + ((buf) << 16) + 32768 + ((h) << 14) + wave1024); \
    gload_lds16(_s + rowK64, lds + ((buf) << 16) + 32768 + ((h) << 14) + 8192 + wave1024); \
} while (0)

#define READ_A(buf, g) do { \
    _Pragma("unroll") \
    for (int m = 0; m < 4; ++m) { \
        const int _b = ((buf) << 16) + regA + rA + ((((g) << 2) + m) << 11); \
        a[m][0] = *reinterpret_cast<const bf16x8*>(lds + _b + low0); \
        a[m][1] = *reinterpret_cast<const bf16x8*>(lds + _b + low1); \
    } \
} while (0)

#define READ_B0(buf) do { \
    _Pragma("unroll") \
    for (int n = 0; n < 2; ++n) { \
        const int _b = ((buf) << 16) + regB + rB + (n << 11); \
        b0[n][0] = *reinterpret_cast<const bf16x8*>(lds + _b + low0); \
        b0[n][1] = *reinterpret_cast<const bf16x8*>(lds + _b + low1); \
    } \
} while (0)

#define READ_B1(buf) do { \
    _Pragma("unroll") \
    for (int n = 0; n < 2; ++n) { \
        const int _b = ((buf) << 16) + regB + rB + ((n + 2) << 11); \
        b1[n][0] = *reinterpret_cast<const bf16x8*>(lds + _b + low0); \
        b1[n][1] = *reinterpret_cast<const bf16x8*>(lds + _b + low1); \
    } \
} while (0)

#define MM(bx, mb, nb) do { \
    __builtin_amdgcn_s_setprio(1); \
    _Pragma("unroll") \
    for (int m = 0; m < 4; ++m) \
        _Pragma("unroll") \
        for (int n = 0; n < 2; ++n) \
            _Pragma("unroll") \
            for (int s = 0; s < 2; ++s) \
                acc[(mb) + m][(nb) + n] = __builtin_amdgcn_mfma_f32_16x16x32_bf16( \
                    a[m][s], bx[n][s], acc[(mb) + m][(nb) + n], 0, 0, 0); \
    __builtin_amdgcn_s_setprio(0); \
} while (0)

#define PH_SYNC() do { SCHEDB(); BARRIER(); LGKM0(); SCHEDB(); } while (0)
#define PH_END()  do { SCHEDB(); BARRIER(); SCHEDB(); } while (0)

    const int NT = K >> 6;   // K-tiles of 64 (even for all our shapes)

    // ---- prologue: tile0 -> buf0 (all 4 halves), tile1 -> buf1 (B halves) ----
    STAGE_A(0, 0, 0); STAGE_A(0, 1, 0); STAGE_B(0, 0, 0); STAGE_B(0, 1, 0);
    STAGE_B(1, 0, 1); STAGE_B(1, 1, 1);
    VMW4(); SCHEDB(); BARRIER();

    for (int it = 0; it < (NT >> 1); ++it) {
        const int t1  = 2 * it + 1;
        const int tn0 = 2 * it + 2;
        const int tn1 = 2 * it + 3;
        const bool st = (it + 1 < (NT >> 1));

        // phase 1: buf0 reads {A m0-3, B n0-1}; stage buf1.A0(t1)
        READ_A(0, 0); READ_B0(0);
        STAGE_A(1, 0, t1);
        PH_SYNC(); MM(b0, 0, 0); PH_END();

        // phase 2: buf0 reads {B n2-3}; stage buf1.A1(t1)
        READ_B1(0);
        STAGE_A(1, 1, t1);
        PH_SYNC(); MM(b1, 0, 2); PH_END();

        // phase 3: buf0 reads {A m4-7}; stage buf0.B0(tn0)
        READ_A(0, 1);
        if (st) STAGE_B(0, 0, tn0);
        PH_SYNC(); MM(b1, 4, 2); PH_END();

        // phase 4: stage buf0.B1(tn0); counted vmcnt
        if (st) { STAGE_B(0, 1, tn0); VMW4(); } else { VMW0(); }
        PH_SYNC(); MM(b0, 4, 0); PH_END();

        // phase 5: buf1 reads {A m0-3, B n0-1}; stage buf0.A0(tn0)
        READ_A(1, 0); READ_B0(1);
        if (st) STAGE_A(0, 0, tn0);
        PH_SYNC(); MM(b0, 0, 0); PH_END();

        // phase 6: buf1 reads {B n2-3}; stage buf0.A1(tn0)
        READ_B1(1);
        if (st) STAGE_A(0, 1, tn0);
        PH_SYNC(); MM(b1, 0, 2); PH_END();

        // phase 7: buf1 reads {A m4-7}; stage buf1.B0(tn1)
        READ_A(1, 1);
        if (st) STAGE_B(1, 0, tn1);
        PH_SYNC(); MM(b1, 4, 2); PH_END();

        // phase 8: stage buf1.B1(tn1); counted vmcnt
        if (st) STAGE_B(1, 1, tn1);
        VMW4();
        PH_SYNC(); MM(b0, 4, 0); PH_END();
    }

    // ---- epilogue ----
    float bb[4];
    #pragma unroll
    for (int n = 0; n < 4; ++n)
        bb[n] = bias[bcol + (wc << 6) + (n << 4) + (lane & 15)];

    const int erow0 = brow + (wr << 7) + ((lane >> 4) << 2);
    const int ecol0 = bcol + (wc << 6) + (lane & 15);

    #pragma unroll
    for (int m = 0; m < 8; ++m) {
        #pragma unroll
        for (int i = 0; i < 4; ++i) {
            const int r = erow0 + (m << 4) + i;
            #pragma unroll
            for (int n = 0; n < 4; ++n) {
                const int c = ecol0 + (n << 4);
                float v = acc[m][n][i] + bb[n];
                if (MODE == 0) {
                    v = v > 0.0f ? v : 0.0f;
                    obf[(size_t)r * N + c] = f2bf_bits(v);
                } else {
                    of32[(size_t)r * N + c] = v;
                }
            }
        }
    }
#undef STAGE_A
#undef STAGE_B
#undef READ_A
#undef READ_B0
#undef READ_B1
#undef MM
#undef PH_SYNC
#undef PH_END
}

// ---------- launch ----------
extern "C" void kernel_launch(void* const* d_in, const int* in_sizes, int n_in,
                              void* d_out, int out_size, void* d_ws, size_t ws_size,
                              hipStream_t stream) {
    const float* x   = (const float*)d_in[0];
    const float* We1 = (const float*)d_in[1];
    const float* be1 = (const float*)d_in[2];
    const float* We2 = (const float*)d_in[3];
    const float* be2 = (const float*)d_in[4];
    const float* Wd1 = (const float*)d_in[5];
    const float* bd1 = (const float*)d_in[6];
    const float* Wd2 = (const float*)d_in[7];
    const float* bd2 = (const float*)d_in[8];
    const float* eps = (const float*)d_in[9];

    const int B = 4096, D = 4096, H = 4096, LAT = 512;

    char* ws = (char*)d_ws;
    u16* xb  = (u16*)(ws);                 // B*D bf16
    u16* w1t = (u16*)(ws + 33554432);      // (H x D)
    u16* w2t = (u16*)(ws + 67108864);      // (2LAT x H)
    u16* w3t = (u16*)(ws + 75497472);      // (H x LAT)
    u16* w4t = (u16*)(ws + 79691776);      // (D x H)
    u16* h   = (u16*)(ws + 113246208);     // B*H bf16
    u16* zs  = w1t;                        // aliases (free after GEMM1/2)
    u16* hd  = xb;                         // aliases (free after GEMM1)

    float* recon = (float*)d_out;
    float* mu    = recon + (size_t)B * D;
    float* lv    = mu + (size_t)B * LAT;

    hipFuncSetAttribute(reinterpret_cast<const void*>(gemm256<0>),
                        hipFuncAttributeMaxDynamicSharedMemorySize, 131072);
    hipFuncSetAttribute(reinterpret_cast<const void*>(gemm256<1>),
                        hipFuncAttributeMaxDynamicSharedMemorySize, 131072);

    dim3 tb(32, 8);
    cvt4<<<(B * D / 4 + 255) / 256, 256, 0, stream>>>(x, xb, B * D);
    transpose_cvt<<<dim3(H / 32, D / 32), tb, 0, stream>>>(We1, w1t, D, H);
    transpose_cvt<<<dim3(2 * LAT / 32, H / 32), tb, 0, stream>>>(We2, w2t, H, 2 * LAT);
    transpose_cvt<<<dim3(H / 32, LAT / 32), tb, 0, stream>>>(Wd1, w3t, LAT, H);
    transpose_cvt<<<dim3(D / 32, H / 32), tb, 0, stream>>>(Wd2, w4t, H, D);

    // h = relu(x @ We1 + be1)        M=B, N=H, K=D   (8-phase 256^2)
    gemm256<0><<<(B / 256) * (H / 256), 512, 131072, stream>>>(xb, w1t, be1, h, nullptr, B, H, D);
    // z = h @ We2 + be2 -> mu, logvar  (128^2 kernel, N=1024)
    gemm_bt<2><<<(B / 128) * (2 * LAT / 128), 256, 0, stream>>>(h, w2t, be2, nullptr, mu, lv, B, 2 * LAT, H);
    // zs = mu + exp(0.5*lv)*eps
    sampler<<<(B * LAT + 255) / 256, 256, 0, stream>>>(mu, lv, eps, zs, B * LAT);
    // hd = relu(zs @ Wd1 + bd1)      M=B, N=H, K=LAT (8-phase 256^2)
    gemm256<0><<<(B / 256) * (H / 256), 512, 131072, stream>>>(zs, w3t, bd1, hd, nullptr, B, H, LAT);
    // recon = hd @ Wd2 + bd2         M=B, N=D, K=H   (8-phase 256^2)
    gemm256<1><<<(B / 256) * (D / 256), 512, 131072, stream>>>(hd, w4t, bd2, nullptr, recon, B, D, H);
}

// Round 4
// 440.241 us; speedup vs baseline: 1.4427x; 1.0186x over previous
//
#include <hip/hip_runtime.h>
#include <hip/hip_bf16.h>

typedef __attribute__((ext_vector_type(8))) __bf16 bf16x8;
typedef __attribute__((ext_vector_type(4))) float f32x4;
typedef __attribute__((ext_vector_type(4))) unsigned short ushort4v;
typedef unsigned short u16;

// ---------- helpers ----------
__device__ __forceinline__ u16 f2bf_bits(float f) {
    union { float f; unsigned int u; } x; x.f = f;
    unsigned int r = x.u + 0x7FFFu + ((x.u >> 16) & 1u);   // RNE
    return (u16)(r >> 16);
}

__device__ __forceinline__ void gload_lds16(const void* g, void* l) {
    __builtin_amdgcn_global_load_lds(
        (const __attribute__((address_space(1))) void*)g,
        (__attribute__((address_space(3))) void*)l, 16, 0, 0);
}

#define BARRIER()  __builtin_amdgcn_s_barrier()
#define SCHEDB()   __builtin_amdgcn_sched_barrier(0)
#define LGKM0()    asm volatile("s_waitcnt lgkmcnt(0)" ::: "memory")
#define VMW8()     asm volatile("s_waitcnt vmcnt(8)" ::: "memory")
#define VMW0()     asm volatile("s_waitcnt vmcnt(0)" ::: "memory")

// ---------- f32 -> bf16 convert (contiguous) ----------
__global__ void cvt4(const float* __restrict__ in, u16* __restrict__ out, int n) {
    int i = (blockIdx.x * 256 + threadIdx.x) << 2;
    if (i >= n) return;
    f32x4 v = *reinterpret_cast<const f32x4*>(in + i);
    ushort4v o;
    o.x = f2bf_bits(v.x); o.y = f2bf_bits(v.y);
    o.z = f2bf_bits(v.z); o.w = f2bf_bits(v.w);
    *reinterpret_cast<ushort4v*>(out + i) = o;
}

// ---------- f32 (R x C) -> bf16 transposed (C x R), 64x64 tiles ----------
__global__ __launch_bounds__(256)
void transpose_cvt64(const float* __restrict__ in, u16* __restrict__ out,
                     int R, int C) {
    __shared__ float t[64][67];
    const int c0 = blockIdx.x << 6;
    const int r0 = blockIdx.y << 6;
    const int tx = threadIdx.x & 15;
    const int ty = threadIdx.x >> 4;
    #pragma unroll
    for (int j = 0; j < 4; ++j) {
        f32x4 v = *reinterpret_cast<const f32x4*>(
            &in[(size_t)(r0 + ty + 16 * j) * C + c0 + (tx << 2)]);
        *reinterpret_cast<f32x4*>(&t[ty + 16 * j][tx << 2]) = v;
    }
    __syncthreads();
    const int oc = threadIdx.x >> 2;
    const int rr = (threadIdx.x & 3) << 2;
    #pragma unroll
    for (int j = 0; j < 4; ++j) {
        const int r = rr + 16 * j;
        ushort4v o;
        o.x = f2bf_bits(t[r + 0][oc]);
        o.y = f2bf_bits(t[r + 1][oc]);
        o.z = f2bf_bits(t[r + 2][oc]);
        o.w = f2bf_bits(t[r + 3][oc]);
        *reinterpret_cast<ushort4v*>(&out[(size_t)(c0 + oc) * R + r0 + r]) = o;
    }
}

// ---------- reparameterization ----------
__global__ void sampler(const float* __restrict__ mu, const float* __restrict__ lv,
                        const float* __restrict__ eps, u16* __restrict__ zs, int n) {
    int i = blockIdx.x * 256 + threadIdx.x;
    if (i >= n) return;
    float v = mu[i] + __expf(0.5f * lv[i]) * eps[i];
    zs[i] = f2bf_bits(v);
}

// ---------- 128x128 2-phase GEMM (z-GEMM N=1024 and K=512 GEMM) ----------
template<int MODE>
__global__ __launch_bounds__(256)
void gemm_bt(const u16* __restrict__ A, const u16* __restrict__ Bt,
             const float* __restrict__ bias,
             u16* __restrict__ obf, float* __restrict__ of32, float* __restrict__ olv,
             int M, int N, int K)
{
    __shared__ u16 As[128 * 32];
    __shared__ u16 Bs[128 * 32];

    const int tid  = threadIdx.x;
    const int lane = tid & 63;
    const int w    = tid >> 6;
    const int wr   = w >> 1;
    const int wc   = w & 1;

    const int nbx  = N >> 7;
    const int brow = (blockIdx.x / nbx) << 7;
    const int bcol = (blockIdx.x % nbx) << 7;

    const int srow = (w << 4) + (lane >> 2);
    const int scol = (lane & 3) << 3;
    const size_t aoff0 = (size_t)(brow + srow) * K + scol;
    const size_t aoff1 = (size_t)(brow + 64 + srow) * K + scol;
    const size_t boff0 = (size_t)(bcol + srow) * K + scol;
    const size_t boff1 = (size_t)(bcol + 64 + srow) * K + scol;

    u16* asl0 = &As[(w << 9)];
    u16* asl1 = &As[2048 + (w << 9)];
    u16* bsl0 = &Bs[(w << 9)];
    u16* bsl1 = &Bs[2048 + (w << 9)];

    f32x4 acc[4][4];
    #pragma unroll
    for (int m = 0; m < 4; ++m)
        #pragma unroll
        for (int n = 0; n < 4; ++n)
            acc[m][n] = (f32x4)(0.0f);

    const int ar   = (wr << 6) + (lane & 15);
    const int br   = (wc << 6) + (lane & 15);
    const int koff = (lane >> 4) << 3;

    for (int kt = 0; kt < K; kt += 32) {
        __syncthreads();
        gload_lds16(A  + aoff0 + kt, asl0);
        gload_lds16(A  + aoff1 + kt, asl1);
        gload_lds16(Bt + boff0 + kt, bsl0);
        gload_lds16(Bt + boff1 + kt, bsl1);
        __syncthreads();

        bf16x8 av[4], bv[4];
        #pragma unroll
        for (int m = 0; m < 4; ++m)
            av[m] = *reinterpret_cast<const bf16x8*>(&As[(ar + (m << 4)) * 32 + koff]);
        #pragma unroll
        for (int n = 0; n < 4; ++n)
            bv[n] = *reinterpret_cast<const bf16x8*>(&Bs[(br + (n << 4)) * 32 + koff]);

        #pragma unroll
        for (int m = 0; m < 4; ++m)
            #pragma unroll
            for (int n = 0; n < 4; ++n)
                acc[m][n] = __builtin_amdgcn_mfma_f32_16x16x32_bf16(
                    av[m], bv[n], acc[m][n], 0, 0, 0);
    }

    float bv4[4];
    #pragma unroll
    for (int n = 0; n < 4; ++n)
        bv4[n] = bias[bcol + (wc << 6) + (n << 4) + (lane & 15)];

    const int erow0 = brow + (wr << 6) + ((lane >> 4) << 2);
    const int ecol0 = bcol + (wc << 6) + (lane & 15);

    #pragma unroll
    for (int m = 0; m < 4; ++m) {
        #pragma unroll
        for (int i = 0; i < 4; ++i) {
            const int r = erow0 + (m << 4) + i;
            #pragma unroll
            for (int n = 0; n < 4; ++n) {
                const int c = ecol0 + (n << 4);
                float v = acc[m][n][i] + bv4[n];
                if (MODE == 0) {
                    v = v > 0.0f ? v : 0.0f;
                    obf[(size_t)r * N + c] = f2bf_bits(v);
                } else if (MODE == 1) {
                    of32[(size_t)r * N + c] = v;
                } else {
                    if (c < 512) of32[(size_t)r * 512 + c] = v;
                    else         olv[(size_t)r * 512 + (c - 512)] = v;
                }
            }
        }
    }
}

// ---------- 256x256 8-phase GEMM, lead-4 stage schedule ----------
// Region last-reads: B0 ph1, B1 ph2, A ph1+ph3 (per buffer half-cycle).
// Stages: ph2 B0, ph3 B1, ph4 A0+A1 (buf0); ph6 B0, ph7 B1, ph8 A0+A1 (buf1).
// Waits: vmcnt(8) at end-ph4 / end-ph8 — youngest waited load issued 4 phases prior.
template<int MODE>
__global__ __launch_bounds__(512, 2)
void gemm256(const u16* __restrict__ A, const u16* __restrict__ Bt,
             const float* __restrict__ bias,
             u16* __restrict__ obf, float* __restrict__ of32,
             int M, int N, int K)
{
    extern __shared__ char lds[];
    const int tid  = threadIdx.x;
    const int lane = tid & 63;
    const int w    = tid >> 6;
    const int wr   = w >> 2;
    const int wc   = w & 3;

    int bid = blockIdx.x;
    const int cpx = gridDim.x >> 3;
    bid = (bid & 7) * cpx + (bid >> 3);
    const int nbx  = N >> 8;
    const int brow = (bid / nbx) << 8;
    const int bcol = (bid % nbx) << 8;

    const int srow  = tid >> 3;
    const int scole = (((tid & 7) ^ (srow & 7)) << 4) >> 1;
    const size_t aoff = (size_t)(brow + srow) * K + scole;
    const size_t boff = (size_t)(bcol + srow) * K + scole;
    const size_t rowK64 = (size_t)64 * K;
    const int wave1024 = w << 10;

    const int lo16 = (lane >> 4) << 4;
    const int swzm = (lane & 7) << 4;
    const int low0 = lo16 ^ swzm;
    const int low1 = (64 | lo16) ^ swzm;
    const int rA   = (lane & 15) << 7;
    const int rB   = ((((wc & 1) << 6) | (lane & 15)) << 7);
    const int regA = wr << 14;
    const int regB = 32768 + ((wc >> 1) << 14);

    bf16x8 a[4][2];
    bf16x8 b0[2][2];
    bf16x8 b1[2][2];
    f32x4 acc[8][4];
    #pragma unroll
    for (int m = 0; m < 8; ++m)
        #pragma unroll
        for (int n = 0; n < 4; ++n)
            acc[m][n] = (f32x4)(0.0f);

#define STAGE_A(buf, h, kt) do { \
    const u16* _s = A + aoff + (size_t)(h) * 128 * K + (size_t)(kt) * 64; \
    gload_lds16(_s,          lds + ((buf) << 16) + ((h) << 14) + wave1024); \
    gload_lds16(_s + rowK64, lds + ((buf) << 16) + ((h) << 14) + 8192 + wave1024); \
} while (0)

#define STAGE_B(buf, h, kt) do { \
    const u16* _s = Bt + boff + (size_t)(h) * 128 * K + (size_t)(kt) * 64; \
    gload_lds16(_s,          lds + ((buf) << 16) + 32768 + ((h) << 14) + wave1024); \
    gload_lds16(_s + rowK64, lds + ((buf) << 16) + 32768 + ((h) << 14) + 8192 + wave1024); \
} while (0)

#define READ_A(buf, g) do { \
    _Pragma("unroll") \
    for (int m = 0; m < 4; ++m) { \
        const int _b = ((buf) << 16) + regA + rA + ((((g) << 2) + m) << 11); \
        a[m][0] = *reinterpret_cast<const bf16x8*>(lds + _b + low0); \
        a[m][1] = *reinterpret_cast<const bf16x8*>(lds + _b + low1); \
    } \
} while (0)

#define READ_B0(buf) do { \
    _Pragma("unroll") \
    for (int n = 0; n < 2; ++n) { \
        const int _b = ((buf) << 16) + regB + rB + (n << 11); \
        b0[n][0] = *reinterpret_cast<const bf16x8*>(lds + _b + low0); \
        b0[n][1] = *reinterpret_cast<const bf16x8*>(lds + _b + low1); \
    } \
} while (0)

#define READ_B1(buf) do { \
    _Pragma("unroll") \
    for (int n = 0; n < 2; ++n) { \
        const int _b = ((buf) << 16) + regB + rB + ((n + 2) << 11); \
        b1[n][0] = *reinterpret_cast<const bf16x8*>(lds + _b + low0); \
        b1[n][1] = *reinterpret_cast<const bf16x8*>(lds + _b + low1); \
    } \
} while (0)

#define MM(bx, mb, nb) do { \
    __builtin_amdgcn_s_setprio(1); \
    _Pragma("unroll") \
    for (int m = 0; m < 4; ++m) \
        _Pragma("unroll") \
        for (int n = 0; n < 2; ++n) \
            _Pragma("unroll") \
            for (int s = 0; s < 2; ++s) \
                acc[(mb) + m][(nb) + n] = __builtin_amdgcn_mfma_f32_16x16x32_bf16( \
                    a[m][s], bx[n][s], acc[(mb) + m][(nb) + n], 0, 0, 0); \
    __builtin_amdgcn_s_setprio(0); \
} while (0)

#define PH_SYNC() do { SCHEDB(); BARRIER(); LGKM0(); SCHEDB(); } while (0)
#define PH_END()  do { SCHEDB(); BARRIER(); SCHEDB(); } while (0)

    const int NIT = K >> 7;   // 2 K-tiles of 64 per iteration

    // ---- prologue: tile0 -> buf0 (8 loads), tile1 -> buf1 (8 loads) ----
    STAGE_A(0, 0, 0); STAGE_A(0, 1, 0); STAGE_B(0, 0, 0); STAGE_B(0, 1, 0);
    STAGE_A(1, 0, 1); STAGE_A(1, 1, 1); STAGE_B(1, 0, 1); STAGE_B(1, 1, 1);
    VMW8(); SCHEDB(); BARRIER();

    for (int it = 0; it < NIT; ++it) {
        const int tn0 = 2 * it + 2;
        const int tn1 = 2 * it + 3;
        const bool st = (it + 1 < NIT);

        // ph1: read buf0 {A g0, B0}
        READ_A(0, 0); READ_B0(0);
        PH_SYNC(); MM(b0, 0, 0); PH_END();

        // ph2: read buf0 {B1}; stage buf0.B0 <- tn0   (B0 last read ph1)
        READ_B1(0);
        if (st) STAGE_B(0, 0, tn0);
        PH_SYNC(); MM(b1, 0, 2); PH_END();

        // ph3: read buf0 {A g1}; stage buf0.B1 <- tn0 (B1 last read ph2)
        READ_A(0, 1);
        if (st) STAGE_B(0, 1, tn0);
        PH_SYNC(); MM(b1, 4, 2); PH_END();

        // ph4: stage buf0.{A0,A1} <- tn0 (A last read ph3); wait prev buf1 stages
        if (st) { STAGE_A(0, 0, tn0); STAGE_A(0, 1, tn0); }
        PH_SYNC(); MM(b0, 4, 0);
        if (st) VMW8(); else VMW0();
        SCHEDB(); BARRIER(); SCHEDB();

        // ph5: read buf1 {A g0, B0}
        READ_A(1, 0); READ_B0(1);
        PH_SYNC(); MM(b0, 0, 0); PH_END();

        // ph6: read buf1 {B1}; stage buf1.B0 <- tn1
        READ_B1(1);
        if (st) STAGE_B(1, 0, tn1);
        PH_SYNC(); MM(b1, 0, 2); PH_END();

        // ph7: read buf1 {A g1}; stage buf1.B1 <- tn1
        READ_A(1, 1);
        if (st) STAGE_B(1, 1, tn1);
        PH_SYNC(); MM(b1, 4, 2); PH_END();

        // ph8: stage buf1.{A0,A1} <- tn1 (A last read ph7); wait this-iter buf0 stages
        if (st) { STAGE_A(1, 0, tn1); STAGE_A(1, 1, tn1); }
        PH_SYNC(); MM(b0, 4, 0);
        if (st) VMW8();
        SCHEDB(); BARRIER(); SCHEDB();
    }

    // ---- epilogue ----
    float bb[4];
    #pragma unroll
    for (int n = 0; n < 4; ++n)
        bb[n] = bias[bcol + (wc << 6) + (n << 4) + (lane & 15)];

    const int erow0 = brow + (wr << 7) + ((lane >> 4) << 2);
    const int ecol0 = bcol + (wc << 6) + (lane & 15);

    #pragma unroll
    for (int m = 0; m < 8; ++m) {
        #pragma unroll
        for (int i = 0; i < 4; ++i) {
            const int r = erow0 + (m << 4) + i;
            #pragma unroll
            for (int n = 0; n < 4; ++n) {
                const int c = ecol0 + (n << 4);
                float v = acc[m][n][i] + bb[n];
                if (MODE == 0) {
                    v = v > 0.0f ? v : 0.0f;
                    obf[(size_t)r * N + c] = f2bf_bits(v);
                } else {
                    of32[(size_t)r * N + c] = v;
                }
            }
        }
    }
#undef STAGE_A
#undef STAGE_B
#undef READ_A
#undef READ_B0
#undef READ_B1
#undef MM
#undef PH_SYNC
#undef PH_END
}

// ---------- launch ----------
extern "C" void kernel_launch(void* const* d_in, const int* in_sizes, int n_in,
                              void* d_out, int out_size, void* d_ws, size_t ws_size,
                              hipStream_t stream) {
    const float* x   = (const float*)d_in[0];
    const float* We1 = (const float*)d_in[1];
    const float* be1 = (const float*)d_in[2];
    const float* We2 = (const float*)d_in[3];
    const float* be2 = (const float*)d_in[4];
    const float* Wd1 = (const float*)d_in[5];
    const float* bd1 = (const float*)d_in[6];
    const float* Wd2 = (const float*)d_in[7];
    const float* bd2 = (const float*)d_in[8];
    const float* eps = (const float*)d_in[9];

    const int B = 4096, D = 4096, H = 4096, LAT = 512;

    char* ws = (char*)d_ws;
    u16* xb  = (u16*)(ws);
    u16* w1t = (u16*)(ws + 33554432);
    u16* w2t = (u16*)(ws + 67108864);
    u16* w3t = (u16*)(ws + 75497472);
    u16* w4t = (u16*)(ws + 79691776);
    u16* h   = (u16*)(ws + 113246208);
    u16* zs  = w1t;
    u16* hd  = xb;

    float* recon = (float*)d_out;
    float* mu    = recon + (size_t)B * D;
    float* lv    = mu + (size_t)B * LAT;

    hipFuncSetAttribute(reinterpret_cast<const void*>(gemm256<0>),
                        hipFuncAttributeMaxDynamicSharedMemorySize, 131072);
    hipFuncSetAttribute(reinterpret_cast<const void*>(gemm256<1>),
                        hipFuncAttributeMaxDynamicSharedMemorySize, 131072);

    cvt4<<<(B * D / 4 + 255) / 256, 256, 0, stream>>>(x, xb, B * D);
    transpose_cvt64<<<dim3(H / 64, D / 64), 256, 0, stream>>>(We1, w1t, D, H);
    transpose_cvt64<<<dim3(2 * LAT / 64, H / 64), 256, 0, stream>>>(We2, w2t, H, 2 * LAT);
    transpose_cvt64<<<dim3(H / 64, LAT / 64), 256, 0, stream>>>(Wd1, w3t, LAT, H);
    transpose_cvt64<<<dim3(D / 64, H / 64), 256, 0, stream>>>(Wd2, w4t, H, D);

    // h = relu(x @ We1 + be1)        M=B, N=H, K=D   (8-phase 256^2, lead-4)
    gemm256<0><<<(B / 256) * (H / 256), 512, 131072, stream>>>(xb, w1t, be1, h, nullptr, B, H, D);
    // z = h @ We2 + be2 -> mu, logvar  (128^2, N=1024)
    gemm_bt<2><<<(B / 128) * (2 * LAT / 128), 256, 0, stream>>>(h, w2t, be2, nullptr, mu, lv, B, 2 * LAT, H);
    // zs = mu + exp(0.5*lv)*eps
    sampler<<<(B * LAT + 255) / 256, 256, 0, stream>>>(mu, lv, eps, zs, B * LAT);
    // hd = relu(zs @ Wd1 + bd1)      M=B, N=H, K=LAT (128^2: K too small for gemm256 pipeline)
    gemm_bt<0><<<(B / 128) * (H / 128), 256, 0, stream>>>(zs, w3t, bd1, hd, nullptr, nullptr, B, H, LAT);
    // recon = hd @ Wd2 + bd2         M=B, N=D, K=H   (8-phase 256^2, lead-4)
    gemm256<1><<<(B / 256) * (D / 256), 512, 131072, stream>>>(hd, w4t, bd2, nullptr, recon, B, D, H);
}

// Round 5
// 431.519 us; speedup vs baseline: 1.4719x; 1.0202x over previous
//
#include <hip/hip_runtime.h>
#include <hip/hip_bf16.h>

typedef __attribute__((ext_vector_type(8))) __bf16 bf16x8;
typedef __attribute__((ext_vector_type(4))) float f32x4;
typedef __attribute__((ext_vector_type(4))) unsigned short ushort4v;
typedef unsigned short u16;

// ---------- helpers ----------
__device__ __forceinline__ u16 f2bf_bits(float f) {
    union { float f; unsigned int u; } x; x.f = f;
    unsigned int r = x.u + 0x7FFFu + ((x.u >> 16) & 1u);   // RNE
    return (u16)(r >> 16);
}

__device__ __forceinline__ void gload_lds16(const void* g, void* l) {
    __builtin_amdgcn_global_load_lds(
        (const __attribute__((address_space(1))) void*)g,
        (__attribute__((address_space(3))) void*)l, 16, 0, 0);
}

#define BARRIER()  __builtin_amdgcn_s_barrier()
#define LGKM0()    asm volatile("s_waitcnt lgkmcnt(0)" ::: "memory")
#define VMW8()     asm volatile("s_waitcnt vmcnt(8)" ::: "memory")
#define VMW0()     asm volatile("s_waitcnt vmcnt(0)" ::: "memory")

// ---------- f32 -> bf16 convert (contiguous) ----------
__global__ void cvt4(const float* __restrict__ in, u16* __restrict__ out, int n) {
    int i = (blockIdx.x * 256 + threadIdx.x) << 2;
    if (i >= n) return;
    f32x4 v = *reinterpret_cast<const f32x4*>(in + i);
    ushort4v o;
    o.x = f2bf_bits(v.x); o.y = f2bf_bits(v.y);
    o.z = f2bf_bits(v.z); o.w = f2bf_bits(v.w);
    *reinterpret_cast<ushort4v*>(out + i) = o;
}

// ---------- f32 (R x C) -> bf16 transposed (C x R), 64x64 tiles ----------
__global__ __launch_bounds__(256)
void transpose_cvt64(const float* __restrict__ in, u16* __restrict__ out,
                     int R, int C) {
    __shared__ float t[64][67];
    const int c0 = blockIdx.x << 6;
    const int r0 = blockIdx.y << 6;
    const int tx = threadIdx.x & 15;
    const int ty = threadIdx.x >> 4;
    #pragma unroll
    for (int j = 0; j < 4; ++j) {
        f32x4 v = *reinterpret_cast<const f32x4*>(
            &in[(size_t)(r0 + ty + 16 * j) * C + c0 + (tx << 2)]);
        *reinterpret_cast<f32x4*>(&t[ty + 16 * j][tx << 2]) = v;
    }
    __syncthreads();
    const int oc = threadIdx.x >> 2;
    const int rr = (threadIdx.x & 3) << 2;
    #pragma unroll
    for (int j = 0; j < 4; ++j) {
        const int r = rr + 16 * j;
        ushort4v o;
        o.x = f2bf_bits(t[r + 0][oc]);
        o.y = f2bf_bits(t[r + 1][oc]);
        o.z = f2bf_bits(t[r + 2][oc]);
        o.w = f2bf_bits(t[r + 3][oc]);
        *reinterpret_cast<ushort4v*>(&out[(size_t)(c0 + oc) * R + r0 + r]) = o;
    }
}

// ---------- reparameterization ----------
__global__ void sampler(const float* __restrict__ mu, const float* __restrict__ lv,
                        const float* __restrict__ eps, u16* __restrict__ zs, int n) {
    int i = blockIdx.x * 256 + threadIdx.x;
    if (i >= n) return;
    float v = mu[i] + __expf(0.5f * lv[i]) * eps[i];
    zs[i] = f2bf_bits(v);
}

// ---------- 128x128 2-phase GEMM (z-GEMM N=1024 and K=512 GEMM) ----------
template<int MODE>
__global__ __launch_bounds__(256)
void gemm_bt(const u16* __restrict__ A, const u16* __restrict__ Bt,
             const float* __restrict__ bias,
             u16* __restrict__ obf, float* __restrict__ of32, float* __restrict__ olv,
             int M, int N, int K)
{
    __shared__ u16 As[128 * 32];
    __shared__ u16 Bs[128 * 32];

    const int tid  = threadIdx.x;
    const int lane = tid & 63;
    const int w    = tid >> 6;
    const int wr   = w >> 1;
    const int wc   = w & 1;

    const int nbx  = N >> 7;
    const int brow = (blockIdx.x / nbx) << 7;
    const int bcol = (blockIdx.x % nbx) << 7;

    const int srow = (w << 4) + (lane >> 2);
    const int scol = (lane & 3) << 3;
    const size_t aoff0 = (size_t)(brow + srow) * K + scol;
    const size_t aoff1 = (size_t)(brow + 64 + srow) * K + scol;
    const size_t boff0 = (size_t)(bcol + srow) * K + scol;
    const size_t boff1 = (size_t)(bcol + 64 + srow) * K + scol;

    u16* asl0 = &As[(w << 9)];
    u16* asl1 = &As[2048 + (w << 9)];
    u16* bsl0 = &Bs[(w << 9)];
    u16* bsl1 = &Bs[2048 + (w << 9)];

    f32x4 acc[4][4];
    #pragma unroll
    for (int m = 0; m < 4; ++m)
        #pragma unroll
        for (int n = 0; n < 4; ++n)
            acc[m][n] = (f32x4)(0.0f);

    const int ar   = (wr << 6) + (lane & 15);
    const int br   = (wc << 6) + (lane & 15);
    const int koff = (lane >> 4) << 3;

    for (int kt = 0; kt < K; kt += 32) {
        __syncthreads();
        gload_lds16(A  + aoff0 + kt, asl0);
        gload_lds16(A  + aoff1 + kt, asl1);
        gload_lds16(Bt + boff0 + kt, bsl0);
        gload_lds16(Bt + boff1 + kt, bsl1);
        __syncthreads();

        bf16x8 av[4], bv[4];
        #pragma unroll
        for (int m = 0; m < 4; ++m)
            av[m] = *reinterpret_cast<const bf16x8*>(&As[(ar + (m << 4)) * 32 + koff]);
        #pragma unroll
        for (int n = 0; n < 4; ++n)
            bv[n] = *reinterpret_cast<const bf16x8*>(&Bs[(br + (n << 4)) * 32 + koff]);

        #pragma unroll
        for (int m = 0; m < 4; ++m)
            #pragma unroll
            for (int n = 0; n < 4; ++n)
                acc[m][n] = __builtin_amdgcn_mfma_f32_16x16x32_bf16(
                    av[m], bv[n], acc[m][n], 0, 0, 0);
    }

    float bv4[4];
    #pragma unroll
    for (int n = 0; n < 4; ++n)
        bv4[n] = bias[bcol + (wc << 6) + (n << 4) + (lane & 15)];

    const int erow0 = brow + (wr << 6) + ((lane >> 4) << 2);
    const int ecol0 = bcol + (wc << 6) + (lane & 15);

    #pragma unroll
    for (int m = 0; m < 4; ++m) {
        #pragma unroll
        for (int i = 0; i < 4; ++i) {
            const int r = erow0 + (m << 4) + i;
            #pragma unroll
            for (int n = 0; n < 4; ++n) {
                const int c = ecol0 + (n << 4);
                float v = acc[m][n][i] + bv4[n];
                if (MODE == 0) {
                    v = v > 0.0f ? v : 0.0f;
                    obf[(size_t)r * N + c] = f2bf_bits(v);
                } else if (MODE == 1) {
                    of32[(size_t)r * N + c] = v;
                } else {
                    if (c < 512) of32[(size_t)r * 512 + c] = v;
                    else         olv[(size_t)r * 512 + (c - 512)] = v;
                }
            }
        }
    }
}

// ---------- 256x256 8-phase GEMM ----------
// Round-4 schedule (proven race-free), minus sched_barrier walls (let the
// compiler bury body VALU under the MFMA pipe), minus `if(st)` branches
// (clamped tile indices; dead stages hit regions never read again).
template<int MODE>
__global__ __launch_bounds__(512, 2)
void gemm256(const u16* __restrict__ A, const u16* __restrict__ Bt,
             const float* __restrict__ bias,
             u16* __restrict__ obf, float* __restrict__ of32,
             int M, int N, int K)
{
    extern __shared__ char lds[];
    const int tid  = threadIdx.x;
    const int lane = tid & 63;
    const int w    = tid >> 6;
    const int wr   = w >> 2;
    const int wc   = w & 3;

    int bid = blockIdx.x;
    const int cpx = gridDim.x >> 3;
    bid = (bid & 7) * cpx + (bid >> 3);
    const int nbx  = N >> 8;
    const int brow = (bid / nbx) << 8;
    const int bcol = (bid % nbx) << 8;

    const int srow  = tid >> 3;
    const int scole = (((tid & 7) ^ (srow & 7)) << 4) >> 1;
    const size_t aoff = (size_t)(brow + srow) * K + scole;
    const size_t boff = (size_t)(bcol + srow) * K + scole;
    const size_t rowK64 = (size_t)64 * K;
    const int wave1024 = w << 10;

    const int lo16 = (lane >> 4) << 4;
    const int swzm = (lane & 7) << 4;
    const int low0 = lo16 ^ swzm;
    const int low1 = (64 | lo16) ^ swzm;
    const int rA   = (lane & 15) << 7;
    const int rB   = ((((wc & 1) << 6) | (lane & 15)) << 7);
    const int regA = wr << 14;
    const int regB = 32768 + ((wc >> 1) << 14);

    bf16x8 a[4][2];
    bf16x8 b0[2][2];
    bf16x8 b1[2][2];
    f32x4 acc[8][4];
    #pragma unroll
    for (int m = 0; m < 8; ++m)
        #pragma unroll
        for (int n = 0; n < 4; ++n)
            acc[m][n] = (f32x4)(0.0f);

#define STAGE_A(buf, h, kt) do { \
    const u16* _s = A + aoff + (size_t)(h) * 128 * K + (size_t)(kt) * 64; \
    gload_lds16(_s,          lds + ((buf) << 16) + ((h) << 14) + wave1024); \
    gload_lds16(_s + rowK64, lds + ((buf) << 16) + ((h) << 14) + 8192 + wave1024); \
} while (0)

#define STAGE_B(buf, h, kt) do { \
    const u16* _s = Bt + boff + (size_t)(h) * 128 * K + (size_t)(kt) * 64; \
    gload_lds16(_s,          lds + ((buf) << 16) + 32768 + ((h) << 14) + wave1024); \
    gload_lds16(_s + rowK64, lds + ((buf) << 16) + 32768 + ((h) << 14) + 8192 + wave1024); \
} while (0)

#define READ_A(buf, g) do { \
    _Pragma("unroll") \
    for (int m = 0; m < 4; ++m) { \
        const int _b = ((buf) << 16) + regA + rA + ((((g) << 2) + m) << 11); \
        a[m][0] = *reinterpret_cast<const bf16x8*>(lds + _b + low0); \
        a[m][1] = *reinterpret_cast<const bf16x8*>(lds + _b + low1); \
    } \
} while (0)

#define READ_B0(buf) do { \
    _Pragma("unroll") \
    for (int n = 0; n < 2; ++n) { \
        const int _b = ((buf) << 16) + regB + rB + (n << 11); \
        b0[n][0] = *reinterpret_cast<const bf16x8*>(lds + _b + low0); \
        b0[n][1] = *reinterpret_cast<const bf16x8*>(lds + _b + low1); \
    } \
} while (0)

#define READ_B1(buf) do { \
    _Pragma("unroll") \
    for (int n = 0; n < 2; ++n) { \
        const int _b = ((buf) << 16) + regB + rB + ((n + 2) << 11); \
        b1[n][0] = *reinterpret_cast<const bf16x8*>(lds + _b + low0); \
        b1[n][1] = *reinterpret_cast<const bf16x8*>(lds + _b + low1); \
    } \
} while (0)

#define MM(bx, mb, nb) do { \
    __builtin_amdgcn_s_setprio(1); \
    _Pragma("unroll") \
    for (int m = 0; m < 4; ++m) \
        _Pragma("unroll") \
        for (int n = 0; n < 2; ++n) \
            _Pragma("unroll") \
            for (int s = 0; s < 2; ++s) \
                acc[(mb) + m][(nb) + n] = __builtin_amdgcn_mfma_f32_16x16x32_bf16( \
                    a[m][s], bx[n][s], acc[(mb) + m][(nb) + n], 0, 0, 0); \
    __builtin_amdgcn_s_setprio(0); \
} while (0)

#define PH_SYNC() do { BARRIER(); LGKM0(); } while (0)
#define PH_END()  do { BARRIER(); } while (0)

    const int NT  = K >> 6;   // K-tiles of 64
    const int NIT = K >> 7;   // 2 K-tiles per iteration

    // ---- prologue: tile0 -> buf0 (8 loads), tile1 -> buf1 (8 loads) ----
    STAGE_A(0, 0, 0); STAGE_A(0, 1, 0); STAGE_B(0, 0, 0); STAGE_B(0, 1, 0);
    STAGE_A(1, 0, 1); STAGE_A(1, 1, 1); STAGE_B(1, 0, 1); STAGE_B(1, 1, 1);
    VMW8(); BARRIER();

    for (int it = 0; it < NIT; ++it) {
        const int tn0r = 2 * it + 2;
        const int tn1r = 2 * it + 3;
        const int tn0 = tn0r < NT ? tn0r : NT - 1;   // clamp: dead stages on last iter
        const int tn1 = tn1r < NT ? tn1r : NT - 1;

        // ph1: read buf0 {A g0, B0}
        READ_A(0, 0); READ_B0(0);
        PH_SYNC(); MM(b0, 0, 0); PH_END();

        // ph2: read buf0 {B1}; stage buf0.B0 <- tn0   (B0 last read ph1)
        READ_B1(0);
        STAGE_B(0, 0, tn0);
        PH_SYNC(); MM(b1, 0, 2); PH_END();

        // ph3: read buf0 {A g1}; stage buf0.B1 <- tn0 (B1 last read ph2)
        READ_A(0, 1);
        STAGE_B(0, 1, tn0);
        PH_SYNC(); MM(b1, 4, 2); PH_END();

        // ph4: stage buf0.{A0,A1} <- tn0 (A last read ph3); wait prev buf1 stages
        STAGE_A(0, 0, tn0); STAGE_A(0, 1, tn0);
        PH_SYNC(); MM(b0, 4, 0);
        VMW8();
        BARRIER();

        // ph5: read buf1 {A g0, B0}
        READ_A(1, 0); READ_B0(1);
        PH_SYNC(); MM(b0, 0, 0); PH_END();

        // ph6: read buf1 {B1}; stage buf1.B0 <- tn1
        READ_B1(1);
        STAGE_B(1, 0, tn1);
        PH_SYNC(); MM(b1, 0, 2); PH_END();

        // ph7: read buf1 {A g1}; stage buf1.B1 <- tn1
        READ_A(1, 1);
        STAGE_B(1, 1, tn1);
        PH_SYNC(); MM(b1, 4, 2); PH_END();

        // ph8: stage buf1.{A0,A1} <- tn1 (A last read ph7); wait this-iter buf0 stages
        STAGE_A(1, 0, tn1); STAGE_A(1, 1, tn1);
        PH_SYNC(); MM(b0, 4, 0);
        VMW8();
        BARRIER();
    }
    VMW0();

    // ---- epilogue ----
    float bb[4];
    #pragma unroll
    for (int n = 0; n < 4; ++n)
        bb[n] = bias[bcol + (wc << 6) + (n << 4) + (lane & 15)];

    const int erow0 = brow + (wr << 7) + ((lane >> 4) << 2);
    const int ecol0 = bcol + (wc << 6) + (lane & 15);

    #pragma unroll
    for (int m = 0; m < 8; ++m) {
        #pragma unroll
        for (int i = 0; i < 4; ++i) {
            const int r = erow0 + (m << 4) + i;
            #pragma unroll
            for (int n = 0; n < 4; ++n) {
                const int c = ecol0 + (n << 4);
                float v = acc[m][n][i] + bb[n];
                if (MODE == 0) {
                    v = v > 0.0f ? v : 0.0f;
                    obf[(size_t)r * N + c] = f2bf_bits(v);
                } else {
                    of32[(size_t)r * N + c] = v;
                }
            }
        }
    }
#undef STAGE_A
#undef STAGE_B
#undef READ_A
#undef READ_B0
#undef READ_B1
#undef MM
#undef PH_SYNC
#undef PH_END
}

// ---------- launch ----------
extern "C" void kernel_launch(void* const* d_in, const int* in_sizes, int n_in,
                              void* d_out, int out_size, void* d_ws, size_t ws_size,
                              hipStream_t stream) {
    const float* x   = (const float*)d_in[0];
    const float* We1 = (const float*)d_in[1];
    const float* be1 = (const float*)d_in[2];
    const float* We2 = (const float*)d_in[3];
    const float* be2 = (const float*)d_in[4];
    const float* Wd1 = (const float*)d_in[5];
    const float* bd1 = (const float*)d_in[6];
    const float* Wd2 = (const float*)d_in[7];
    const float* bd2 = (const float*)d_in[8];
    const float* eps = (const float*)d_in[9];

    const int B = 4096, D = 4096, H = 4096, LAT = 512;

    char* ws = (char*)d_ws;
    u16* xb  = (u16*)(ws);
    u16* w1t = (u16*)(ws + 33554432);
    u16* w2t = (u16*)(ws + 67108864);
    u16* w3t = (u16*)(ws + 75497472);
    u16* w4t = (u16*)(ws + 79691776);
    u16* h   = (u16*)(ws + 113246208);
    u16* zs  = w1t;
    u16* hd  = xb;

    float* recon = (float*)d_out;
    float* mu    = recon + (size_t)B * D;
    float* lv    = mu + (size_t)B * LAT;

    hipFuncSetAttribute(reinterpret_cast<const void*>(gemm256<0>),
                        hipFuncAttributeMaxDynamicSharedMemorySize, 131072);
    hipFuncSetAttribute(reinterpret_cast<const void*>(gemm256<1>),
                        hipFuncAttributeMaxDynamicSharedMemorySize, 131072);

    cvt4<<<(B * D / 4 + 255) / 256, 256, 0, stream>>>(x, xb, B * D);
    transpose_cvt64<<<dim3(H / 64, D / 64), 256, 0, stream>>>(We1, w1t, D, H);
    transpose_cvt64<<<dim3(2 * LAT / 64, H / 64), 256, 0, stream>>>(We2, w2t, H, 2 * LAT);
    transpose_cvt64<<<dim3(H / 64, LAT / 64), 256, 0, stream>>>(Wd1, w3t, LAT, H);
    transpose_cvt64<<<dim3(D / 64, H / 64), 256, 0, stream>>>(Wd2, w4t, H, D);

    // h = relu(x @ We1 + be1)        M=B, N=H, K=D   (8-phase 256^2)
    gemm256<0><<<(B / 256) * (H / 256), 512, 131072, stream>>>(xb, w1t, be1, h, nullptr, B, H, D);
    // z = h @ We2 + be2 -> mu, logvar  (128^2, N=1024)
    gemm_bt<2><<<(B / 128) * (2 * LAT / 128), 256, 0, stream>>>(h, w2t, be2, nullptr, mu, lv, B, 2 * LAT, H);
    // zs = mu + exp(0.5*lv)*eps
    sampler<<<(B * LAT + 255) / 256, 256, 0, stream>>>(mu, lv, eps, zs, B * LAT);
    // hd = relu(zs @ Wd1 + bd1)      M=B, N=H, K=LAT (128^2: K too small for deep pipeline)
    gemm_bt<0><<<(B / 128) * (H / 128), 256, 0, stream>>>(zs, w3t, bd1, hd, nullptr, nullptr, B, H, LAT);
    // recon = hd @ Wd2 + bd2         M=B, N=D, K=H   (8-phase 256^2)
    gemm256<1><<<(B / 256) * (D / 256), 512, 131072, stream>>>(hd, w4t, bd2, nullptr, recon, B, D, H);
}

// Round 6
// 419.147 us; speedup vs baseline: 1.5153x; 1.0295x over previous
//
#include <hip/hip_runtime.h>
#include <hip/hip_bf16.h>

typedef __attribute__((ext_vector_type(8))) __bf16 bf16x8;
typedef __attribute__((ext_vector_type(4))) float f32x4;
typedef __attribute__((ext_vector_type(4))) unsigned short ushort4v;
typedef unsigned short u16;

// ---------- helpers ----------
__device__ __forceinline__ u16 f2bf_bits(float f) {
    union { float f; unsigned int u; } x; x.f = f;
    unsigned int r = x.u + 0x7FFFu + ((x.u >> 16) & 1u);   // RNE
    return (u16)(r >> 16);
}

__device__ __forceinline__ void gload_lds16(const void* g, void* l) {
    __builtin_amdgcn_global_load_lds(
        (const __attribute__((address_space(1))) void*)g,
        (__attribute__((address_space(3))) void*)l, 16, 0, 0);
}

#define BARRIER()  __builtin_amdgcn_s_barrier()
#define LGKM0()    asm volatile("s_waitcnt lgkmcnt(0)" ::: "memory")
#define VMW8()     asm volatile("s_waitcnt vmcnt(8)" ::: "memory")
#define VMW4()     asm volatile("s_waitcnt vmcnt(4)" ::: "memory")

// ---------- f32 -> bf16 convert (contiguous) ----------
__global__ void cvt4(const float* __restrict__ in, u16* __restrict__ out, int n) {
    int i = (blockIdx.x * 256 + threadIdx.x) << 2;
    if (i >= n) return;
    f32x4 v = *reinterpret_cast<const f32x4*>(in + i);
    ushort4v o;
    o.x = f2bf_bits(v.x); o.y = f2bf_bits(v.y);
    o.z = f2bf_bits(v.z); o.w = f2bf_bits(v.w);
    *reinterpret_cast<ushort4v*>(out + i) = o;
}

// ---------- f32 (R x C) -> bf16 transposed (C x R), 64x64 tiles ----------
__global__ __launch_bounds__(256)
void transpose_cvt64(const float* __restrict__ in, u16* __restrict__ out,
                     int R, int C) {
    __shared__ float t[64][67];
    const int c0 = blockIdx.x << 6;
    const int r0 = blockIdx.y << 6;
    const int tx = threadIdx.x & 15;
    const int ty = threadIdx.x >> 4;
    #pragma unroll
    for (int j = 0; j < 4; ++j) {
        f32x4 v = *reinterpret_cast<const f32x4*>(
            &in[(size_t)(r0 + ty + 16 * j) * C + c0 + (tx << 2)]);
        *reinterpret_cast<f32x4*>(&t[ty + 16 * j][tx << 2]) = v;
    }
    __syncthreads();
    const int oc = threadIdx.x >> 2;
    const int rr = (threadIdx.x & 3) << 2;
    #pragma unroll
    for (int j = 0; j < 4; ++j) {
        const int r = rr + 16 * j;
        ushort4v o;
        o.x = f2bf_bits(t[r + 0][oc]);
        o.y = f2bf_bits(t[r + 1][oc]);
        o.z = f2bf_bits(t[r + 2][oc]);
        o.w = f2bf_bits(t[r + 3][oc]);
        *reinterpret_cast<ushort4v*>(&out[(size_t)(c0 + oc) * R + r0 + r]) = o;
    }
}

// ---------- reparameterization ----------
__global__ void sampler(const float* __restrict__ mu, const float* __restrict__ lv,
                        const float* __restrict__ eps, u16* __restrict__ zs, int n) {
    int i = blockIdx.x * 256 + threadIdx.x;
    if (i >= n) return;
    float v = mu[i] + __expf(0.5f * lv[i]) * eps[i];
    zs[i] = f2bf_bits(v);
}

// ---------- 128x128 2-phase GEMM (z-GEMM N=1024) ----------
template<int MODE>
__global__ __launch_bounds__(256)
void gemm_bt(const u16* __restrict__ A, const u16* __restrict__ Bt,
             const float* __restrict__ bias,
             u16* __restrict__ obf, float* __restrict__ of32, float* __restrict__ olv,
             int M, int N, int K)
{
    __shared__ u16 As[128 * 32];
    __shared__ u16 Bs[128 * 32];

    const int tid  = threadIdx.x;
    const int lane = tid & 63;
    const int w    = tid >> 6;
    const int wr   = w >> 1;
    const int wc   = w & 1;

    const int nbx  = N >> 7;
    const int brow = (blockIdx.x / nbx) << 7;
    const int bcol = (blockIdx.x % nbx) << 7;

    const int srow = (w << 4) + (lane >> 2);
    const int scol = (lane & 3) << 3;
    const size_t aoff0 = (size_t)(brow + srow) * K + scol;
    const size_t aoff1 = (size_t)(brow + 64 + srow) * K + scol;
    const size_t boff0 = (size_t)(bcol + srow) * K + scol;
    const size_t boff1 = (size_t)(bcol + 64 + srow) * K + scol;

    u16* asl0 = &As[(w << 9)];
    u16* asl1 = &As[2048 + (w << 9)];
    u16* bsl0 = &Bs[(w << 9)];
    u16* bsl1 = &Bs[2048 + (w << 9)];

    f32x4 acc[4][4];
    #pragma unroll
    for (int m = 0; m < 4; ++m)
        #pragma unroll
        for (int n = 0; n < 4; ++n)
            acc[m][n] = (f32x4)(0.0f);

    const int ar   = (wr << 6) + (lane & 15);
    const int br   = (wc << 6) + (lane & 15);
    const int koff = (lane >> 4) << 3;

    for (int kt = 0; kt < K; kt += 32) {
        __syncthreads();
        gload_lds16(A  + aoff0 + kt, asl0);
        gload_lds16(A  + aoff1 + kt, asl1);
        gload_lds16(Bt + boff0 + kt, bsl0);
        gload_lds16(Bt + boff1 + kt, bsl1);
        __syncthreads();

        bf16x8 av[4], bv[4];
        #pragma unroll
        for (int m = 0; m < 4; ++m)
            av[m] = *reinterpret_cast<const bf16x8*>(&As[(ar + (m << 4)) * 32 + koff]);
        #pragma unroll
        for (int n = 0; n < 4; ++n)
            bv[n] = *reinterpret_cast<const bf16x8*>(&Bs[(br + (n << 4)) * 32 + koff]);

        #pragma unroll
        for (int m = 0; m < 4; ++m)
            #pragma unroll
            for (int n = 0; n < 4; ++n)
                acc[m][n] = __builtin_amdgcn_mfma_f32_16x16x32_bf16(
                    av[m], bv[n], acc[m][n], 0, 0, 0);
    }

    float bv4[4];
    #pragma unroll
    for (int n = 0; n < 4; ++n)
        bv4[n] = bias[bcol + (wc << 6) + (n << 4) + (lane & 15)];

    const int erow0 = brow + (wr << 6) + ((lane >> 4) << 2);
    const int ecol0 = bcol + (wc << 6) + (lane & 15);

    #pragma unroll
    for (int m = 0; m < 4; ++m) {
        #pragma unroll
        for (int i = 0; i < 4; ++i) {
            const int r = erow0 + (m << 4) + i;
            #pragma unroll
            for (int n = 0; n < 4; ++n) {
                const int c = ecol0 + (n << 4);
                float v = acc[m][n][i] + bv4[n];
                if (MODE == 0) {
                    v = v > 0.0f ? v : 0.0f;
                    obf[(size_t)r * N + c] = f2bf_bits(v);
                } else if (MODE == 1) {
                    of32[(size_t)r * N + c] = v;
                } else {
                    if (c < 512) of32[(size_t)r * 512 + c] = v;
                    else         olv[(size_t)r * 512 + (c - 512)] = v;
                }
            }
        }
    }
}

// ---------- 256x256 8-phase GEMM, reads-under-MFMA rotation ----------
// Phase p region: [sync barrier; lgkmcnt(0); MM(p); issue ds_reads for p+1;
//                  (vmcnt drain at p=3,7); end barrier; stage window]
// Reads execute while the SIMD's MFMA drain (~621 cy) is in flight; their
// latency is covered by the next sync+lgkm. Stage WAR safety identical to r5.
template<int MODE>
__global__ __launch_bounds__(512, 2)
void gemm256(const u16* __restrict__ A, const u16* __restrict__ Bt,
             const float* __restrict__ bias,
             u16* __restrict__ obf, float* __restrict__ of32,
             int M, int N, int K)
{
    extern __shared__ char lds[];
    const int tid  = threadIdx.x;
    const int lane = tid & 63;
    const int w    = tid >> 6;
    const int wr   = w >> 2;
    const int wc   = w & 3;

    int bid = blockIdx.x;
    const int cpx = gridDim.x >> 3;
    bid = (bid & 7) * cpx + (bid >> 3);
    const int nbx  = N >> 8;
    const int brow = (bid / nbx) << 8;
    const int bcol = (bid % nbx) << 8;

    const int srow  = tid >> 3;
    const int scole = (((tid & 7) ^ (srow & 7)) << 4) >> 1;
    const size_t aoff = (size_t)(brow + srow) * K + scole;
    const size_t boff = (size_t)(bcol + srow) * K + scole;
    const size_t rowK64 = (size_t)64 * K;
    const int wave1024 = w << 10;

    const int lo16 = (lane >> 4) << 4;
    const int swzm = (lane & 7) << 4;
    const int low0 = lo16 ^ swzm;
    const int low1 = (64 | lo16) ^ swzm;
    const int rA   = (lane & 15) << 7;
    const int rB   = ((((wc & 1) << 6) | (lane & 15)) << 7);
    const int regA = wr << 14;
    const int regB = 32768 + ((wc >> 1) << 14);

    bf16x8 a[4][2];
    bf16x8 b0[2][2];
    bf16x8 b1[2][2];
    f32x4 acc[8][4];
    #pragma unroll
    for (int m = 0; m < 8; ++m)
        #pragma unroll
        for (int n = 0; n < 4; ++n)
            acc[m][n] = (f32x4)(0.0f);

#define STAGE_A(buf, h, kt) do { \
    const u16* _s = A + aoff + (size_t)(h) * 128 * K + (size_t)(kt) * 64; \
    gload_lds16(_s,          lds + ((buf) << 16) + ((h) << 14) + wave1024); \
    gload_lds16(_s + rowK64, lds + ((buf) << 16) + ((h) << 14) + 8192 + wave1024); \
} while (0)

#define STAGE_B(buf, h, kt) do { \
    const u16* _s = Bt + boff + (size_t)(h) * 128 * K + (size_t)(kt) * 64; \
    gload_lds16(_s,          lds + ((buf) << 16) + 32768 + ((h) << 14) + wave1024); \
    gload_lds16(_s + rowK64, lds + ((buf) << 16) + 32768 + ((h) << 14) + 8192 + wave1024); \
} while (0)

#define READ_A(buf, g) do { \
    _Pragma("unroll") \
    for (int m = 0; m < 4; ++m) { \
        const int _b = ((buf) << 16) + regA + rA + ((((g) << 2) + m) << 11); \
        a[m][0] = *reinterpret_cast<const bf16x8*>(lds + _b + low0); \
        a[m][1] = *reinterpret_cast<const bf16x8*>(lds + _b + low1); \
    } \
} while (0)

#define READ_B0(buf) do { \
    _Pragma("unroll") \
    for (int n = 0; n < 2; ++n) { \
        const int _b = ((buf) << 16) + regB + rB + (n << 11); \
        b0[n][0] = *reinterpret_cast<const bf16x8*>(lds + _b + low0); \
        b0[n][1] = *reinterpret_cast<const bf16x8*>(lds + _b + low1); \
    } \
} while (0)

#define READ_B1(buf) do { \
    _Pragma("unroll") \
    for (int n = 0; n < 2; ++n) { \
        const int _b = ((buf) << 16) + regB + rB + ((n + 2) << 11); \
        b1[n][0] = *reinterpret_cast<const bf16x8*>(lds + _b + low0); \
        b1[n][1] = *reinterpret_cast<const bf16x8*>(lds + _b + low1); \
    } \
} while (0)

#define MM(bx, mb, nb) do { \
    __builtin_amdgcn_s_setprio(1); \
    _Pragma("unroll") \
    for (int m = 0; m < 4; ++m) \
        _Pragma("unroll") \
        for (int n = 0; n < 2; ++n) \
            _Pragma("unroll") \
            for (int s = 0; s < 2; ++s) \
                acc[(mb) + m][(nb) + n] = __builtin_amdgcn_mfma_f32_16x16x32_bf16( \
                    a[m][s], bx[n][s], acc[(mb) + m][(nb) + n], 0, 0, 0); \
    __builtin_amdgcn_s_setprio(0); \
} while (0)

    const int NT  = K >> 6;   // K-tiles of 64
    const int NIT = K >> 7;   // 2 K-tiles per iteration

    // ---- prologue: tile0 -> buf0 (8 loads), tile1 -> buf1 (8 loads) ----
    STAGE_A(0, 0, 0); STAGE_A(0, 1, 0); STAGE_B(0, 0, 0); STAGE_B(0, 1, 0);
    STAGE_A(1, 0, 1); STAGE_A(1, 1, 1); STAGE_B(1, 0, 1); STAGE_B(1, 1, 1);
    VMW8(); BARRIER();
    READ_A(0, 0); READ_B0(0);          // ph1 operands

    for (int it = 0; it < NIT; ++it) {
        const int tn0r = 2 * it + 2;
        const int tn1r = 2 * it + 3;
        const int tn0 = tn0r < NT ? tn0r : NT - 1;   // clamp: dead stages, last iter
        const int tn1 = tn1r < NT ? tn1r : NT - 1;

        // ph1: MM(b0 low) + prefetch-read B1
        BARRIER(); LGKM0();
        MM(b0, 0, 0);
        READ_B1(0);
        BARRIER();
        STAGE_B(0, 0, tn0);                          // W2 (B0 last read pre-ph1)

        // ph2: MM(b1 low) + prefetch-read A g1
        BARRIER(); LGKM0();
        MM(b1, 0, 2);
        READ_A(0, 1);
        BARRIER();
        STAGE_B(0, 1, tn0);                          // W3 (B1 last read ph1-region)

        // ph3: MM(b1 high); drain prev-iter buf1 stages
        BARRIER(); LGKM0();
        MM(b1, 4, 2);
        VMW4();
        BARRIER();
        STAGE_A(0, 0, tn0); STAGE_A(0, 1, tn0);      // W4 (A last read ph2-region)

        // ph4: MM(b0 high) + prefetch-read buf1 {A g0, B0}
        BARRIER(); LGKM0();
        MM(b0, 4, 0);
        READ_A(1, 0); READ_B0(1);
        BARRIER();
        // W5: no stage

        // ph5: MM(b0' low) + prefetch-read B1'
        BARRIER(); LGKM0();
        MM(b0, 0, 0);
        READ_B1(1);
        BARRIER();
        STAGE_B(1, 0, tn1);                          // W6

        // ph6: MM(b1' low) + prefetch-read A g1'
        BARRIER(); LGKM0();
        MM(b1, 0, 2);
        READ_A(1, 1);
        BARRIER();
        STAGE_B(1, 1, tn1);                          // W7

        // ph7: MM(b1' high); drain this-iter buf0 stages
        BARRIER(); LGKM0();
        MM(b1, 4, 2);
        VMW4();
        BARRIER();
        STAGE_A(1, 0, tn1); STAGE_A(1, 1, tn1);      // W8

        // ph8: MM(b0' high) + prefetch-read next-iter buf0 {A g0, B0}
        BARRIER(); LGKM0();
        MM(b0, 4, 0);
        READ_A(0, 0); READ_B0(0);
        BARRIER();
    }

    // ---- epilogue ----
    float bb[4];
    #pragma unroll
    for (int n = 0; n < 4; ++n)
        bb[n] = bias[bcol + (wc << 6) + (n << 4) + (lane & 15)];

    const int erow0 = brow + (wr << 7) + ((lane >> 4) << 2);
    const int ecol0 = bcol + (wc << 6) + (lane & 15);

    #pragma unroll
    for (int m = 0; m < 8; ++m) {
        #pragma unroll
        for (int i = 0; i < 4; ++i) {
            const int r = erow0 + (m << 4) + i;
            #pragma unroll
            for (int n = 0; n < 4; ++n) {
                const int c = ecol0 + (n << 4);
                float v = acc[m][n][i] + bb[n];
                if (MODE == 0) {
                    v = v > 0.0f ? v : 0.0f;
                    obf[(size_t)r * N + c] = f2bf_bits(v);
                } else {
                    of32[(size_t)r * N + c] = v;
                }
            }
        }
    }
#undef STAGE_A
#undef STAGE_B
#undef READ_A
#undef READ_B0
#undef READ_B1
#undef MM
}

// ---------- launch ----------
extern "C" void kernel_launch(void* const* d_in, const int* in_sizes, int n_in,
                              void* d_out, int out_size, void* d_ws, size_t ws_size,
                              hipStream_t stream) {
    const float* x   = (const float*)d_in[0];
    const float* We1 = (const float*)d_in[1];
    const float* be1 = (const float*)d_in[2];
    const float* We2 = (const float*)d_in[3];
    const float* be2 = (const float*)d_in[4];
    const float* Wd1 = (const float*)d_in[5];
    const float* bd1 = (const float*)d_in[6];
    const float* Wd2 = (const float*)d_in[7];
    const float* bd2 = (const float*)d_in[8];
    const float* eps = (const float*)d_in[9];

    const int B = 4096, D = 4096, H = 4096, LAT = 512;

    char* ws = (char*)d_ws;
    u16* xb  = (u16*)(ws);
    u16* w1t = (u16*)(ws + 33554432);
    u16* w2t = (u16*)(ws + 67108864);
    u16* w3t = (u16*)(ws + 75497472);
    u16* w4t = (u16*)(ws + 79691776);
    u16* h   = (u16*)(ws + 113246208);
    u16* zs  = w1t;
    u16* hd  = xb;

    float* recon = (float*)d_out;
    float* mu    = recon + (size_t)B * D;
    float* lv    = mu + (size_t)B * LAT;

    hipFuncSetAttribute(reinterpret_cast<const void*>(gemm256<0>),
                        hipFuncAttributeMaxDynamicSharedMemorySize, 131072);
    hipFuncSetAttribute(reinterpret_cast<const void*>(gemm256<1>),
                        hipFuncAttributeMaxDynamicSharedMemorySize, 131072);

    cvt4<<<(B * D / 4 + 255) / 256, 256, 0, stream>>>(x, xb, B * D);
    transpose_cvt64<<<dim3(H / 64, D / 64), 256, 0, stream>>>(We1, w1t, D, H);
    transpose_cvt64<<<dim3(2 * LAT / 64, H / 64), 256, 0, stream>>>(We2, w2t, H, 2 * LAT);
    transpose_cvt64<<<dim3(H / 64, LAT / 64), 256, 0, stream>>>(Wd1, w3t, LAT, H);
    transpose_cvt64<<<dim3(D / 64, H / 64), 256, 0, stream>>>(Wd2, w4t, H, D);

    // h = relu(x @ We1 + be1)        M=B, N=H, K=D   (256^2 reads-under-MFMA)
    gemm256<0><<<(B / 256) * (H / 256), 512, 131072, stream>>>(xb, w1t, be1, h, nullptr, B, H, D);
    // z = h @ We2 + be2 -> mu, logvar  (128^2, N=1024)
    gemm_bt<2><<<(B / 128) * (2 * LAT / 128), 256, 0, stream>>>(h, w2t, be2, nullptr, mu, lv, B, 2 * LAT, H);
    // zs = mu + exp(0.5*lv)*eps
    sampler<<<(B * LAT + 255) / 256, 256, 0, stream>>>(mu, lv, eps, zs, B * LAT);
    // hd = relu(zs @ Wd1 + bd1)      M=B, N=H, K=LAT (256^2, NIT=4)
    gemm256<0><<<(B / 256) * (H / 256), 512, 131072, stream>>>(zs, w3t, bd1, hd, nullptr, B, H, LAT);
    // recon = hd @ Wd2 + bd2         M=B, N=D, K=H   (256^2 reads-under-MFMA)
    gemm256<1><<<(B / 256) * (D / 256), 512, 131072, stream>>>(hd, w4t, bd2, nullptr, recon, B, D, H);
}

// Round 7
// 414.566 us; speedup vs baseline: 1.5320x; 1.0111x over previous
//
#include <hip/hip_runtime.h>
#include <hip/hip_bf16.h>

typedef __attribute__((ext_vector_type(8))) __bf16 bf16x8;
typedef __attribute__((ext_vector_type(4))) float f32x4;
typedef __attribute__((ext_vector_type(4))) unsigned short ushort4v;
typedef unsigned short u16;

// ---------- helpers ----------
__device__ __forceinline__ u16 f2bf_bits(float f) {
    union { float f; unsigned int u; } x; x.f = f;
    unsigned int r = x.u + 0x7FFFu + ((x.u >> 16) & 1u);   // RNE
    return (u16)(r >> 16);
}

__device__ __forceinline__ void gload_lds16(const void* g, void* l) {
    __builtin_amdgcn_global_load_lds(
        (const __attribute__((address_space(1))) void*)g,
        (__attribute__((address_space(3))) void*)l, 16, 0, 0);
}

#define BARRIER()  __builtin_amdgcn_s_barrier()
#define LGKM0()    asm volatile("s_waitcnt lgkmcnt(0)" ::: "memory")
#define VMW8()     asm volatile("s_waitcnt vmcnt(8)" ::: "memory")

// ---------- f32 -> bf16 convert (contiguous) ----------
__global__ void cvt4(const float* __restrict__ in, u16* __restrict__ out, int n) {
    int i = (blockIdx.x * 256 + threadIdx.x) << 2;
    if (i >= n) return;
    f32x4 v = *reinterpret_cast<const f32x4*>(in + i);
    ushort4v o;
    o.x = f2bf_bits(v.x); o.y = f2bf_bits(v.y);
    o.z = f2bf_bits(v.z); o.w = f2bf_bits(v.w);
    *reinterpret_cast<ushort4v*>(out + i) = o;
}

// ---------- f32 (R x C) -> bf16 transposed (C x R), 64x64 tiles ----------
__global__ __launch_bounds__(256)
void transpose_cvt64(const float* __restrict__ in, u16* __restrict__ out,
                     int R, int C) {
    __shared__ float t[64][67];
    const int c0 = blockIdx.x << 6;
    const int r0 = blockIdx.y << 6;
    const int tx = threadIdx.x & 15;
    const int ty = threadIdx.x >> 4;
    #pragma unroll
    for (int j = 0; j < 4; ++j) {
        f32x4 v = *reinterpret_cast<const f32x4*>(
            &in[(size_t)(r0 + ty + 16 * j) * C + c0 + (tx << 2)]);
        *reinterpret_cast<f32x4*>(&t[ty + 16 * j][tx << 2]) = v;
    }
    __syncthreads();
    const int oc = threadIdx.x >> 2;
    const int rr = (threadIdx.x & 3) << 2;
    #pragma unroll
    for (int j = 0; j < 4; ++j) {
        const int r = rr + 16 * j;
        ushort4v o;
        o.x = f2bf_bits(t[r + 0][oc]);
        o.y = f2bf_bits(t[r + 1][oc]);
        o.z = f2bf_bits(t[r + 2][oc]);
        o.w = f2bf_bits(t[r + 3][oc]);
        *reinterpret_cast<ushort4v*>(&out[(size_t)(c0 + oc) * R + r0 + r]) = o;
    }
}

// ---------- reparameterization ----------
__global__ void sampler(const float* __restrict__ mu, const float* __restrict__ lv,
                        const float* __restrict__ eps, u16* __restrict__ zs, int n) {
    int i = blockIdx.x * 256 + threadIdx.x;
    if (i >= n) return;
    float v = mu[i] + __expf(0.5f * lv[i]) * eps[i];
    zs[i] = f2bf_bits(v);
}

// ---------- 128x128 2-phase GEMM (z-GEMM N=1024) ----------
template<int MODE>
__global__ __launch_bounds__(256)
void gemm_bt(const u16* __restrict__ A, const u16* __restrict__ Bt,
             const float* __restrict__ bias,
             u16* __restrict__ obf, float* __restrict__ of32, float* __restrict__ olv,
             int M, int N, int K)
{
    __shared__ u16 As[128 * 32];
    __shared__ u16 Bs[128 * 32];

    const int tid  = threadIdx.x;
    const int lane = tid & 63;
    const int w    = tid >> 6;
    const int wr   = w >> 1;
    const int wc   = w & 1;

    const int nbx  = N >> 7;
    const int brow = (blockIdx.x / nbx) << 7;
    const int bcol = (blockIdx.x % nbx) << 7;

    const int srow = (w << 4) + (lane >> 2);
    const int scol = (lane & 3) << 3;
    const size_t aoff0 = (size_t)(brow + srow) * K + scol;
    const size_t aoff1 = (size_t)(brow + 64 + srow) * K + scol;
    const size_t boff0 = (size_t)(bcol + srow) * K + scol;
    const size_t boff1 = (size_t)(bcol + 64 + srow) * K + scol;

    u16* asl0 = &As[(w << 9)];
    u16* asl1 = &As[2048 + (w << 9)];
    u16* bsl0 = &Bs[(w << 9)];
    u16* bsl1 = &Bs[2048 + (w << 9)];

    f32x4 acc[4][4];
    #pragma unroll
    for (int m = 0; m < 4; ++m)
        #pragma unroll
        for (int n = 0; n < 4; ++n)
            acc[m][n] = (f32x4)(0.0f);

    const int ar   = (wr << 6) + (lane & 15);
    const int br   = (wc << 6) + (lane & 15);
    const int koff = (lane >> 4) << 3;

    for (int kt = 0; kt < K; kt += 32) {
        __syncthreads();
        gload_lds16(A  + aoff0 + kt, asl0);
        gload_lds16(A  + aoff1 + kt, asl1);
        gload_lds16(Bt + boff0 + kt, bsl0);
        gload_lds16(Bt + boff1 + kt, bsl1);
        __syncthreads();

        bf16x8 av[4], bv[4];
        #pragma unroll
        for (int m = 0; m < 4; ++m)
            av[m] = *reinterpret_cast<const bf16x8*>(&As[(ar + (m << 4)) * 32 + koff]);
        #pragma unroll
        for (int n = 0; n < 4; ++n)
            bv[n] = *reinterpret_cast<const bf16x8*>(&Bs[(br + (n << 4)) * 32 + koff]);

        #pragma unroll
        for (int m = 0; m < 4; ++m)
            #pragma unroll
            for (int n = 0; n < 4; ++n)
                acc[m][n] = __builtin_amdgcn_mfma_f32_16x16x32_bf16(
                    av[m], bv[n], acc[m][n], 0, 0, 0);
    }

    float bv4[4];
    #pragma unroll
    for (int n = 0; n < 4; ++n)
        bv4[n] = bias[bcol + (wc << 6) + (n << 4) + (lane & 15)];

    const int erow0 = brow + (wr << 6) + ((lane >> 4) << 2);
    const int ecol0 = bcol + (wc << 6) + (lane & 15);

    #pragma unroll
    for (int m = 0; m < 4; ++m) {
        #pragma unroll
        for (int i = 0; i < 4; ++i) {
            const int r = erow0 + (m << 4) + i;
            #pragma unroll
            for (int n = 0; n < 4; ++n) {
                const int c = ecol0 + (n << 4);
                float v = acc[m][n][i] + bv4[n];
                if (MODE == 0) {
                    v = v > 0.0f ? v : 0.0f;
                    obf[(size_t)r * N + c] = f2bf_bits(v);
                } else if (MODE == 1) {
                    of32[(size_t)r * N + c] = v;
                } else {
                    if (c < 512) of32[(size_t)r * 512 + c] = v;
                    else         olv[(size_t)r * 512 + (c - 512)] = v;
                }
            }
        }
    }
}

// ---------- 256x256 8-phase GEMM, single-barrier phases ----------
// Phase p: [BAR; lgkmcnt(0); STAGE(assigned); MM(p); (vmcnt(8) ph4/ph8); READ(p+1)]
// Stage of region R sits 2 barriers + 1 region after R's last read-issue;
// in-flight same-phase reads from other waves always target disjoint regions.
// Register WAR (reads overwrite frags last consumed by this MM) forces the
// scheduler to sink ds_reads behind their last consumer MFMA.
template<int MODE>
__global__ __launch_bounds__(512, 2)
void gemm256(const u16* __restrict__ A, const u16* __restrict__ Bt,
             const float* __restrict__ bias,
             u16* __restrict__ obf, float* __restrict__ of32,
             int M, int N, int K)
{
    extern __shared__ char lds[];
    const int tid  = threadIdx.x;
    const int lane = tid & 63;
    const int w    = tid >> 6;
    const int wr   = w >> 2;
    const int wc   = w & 3;

    int bid = blockIdx.x;
    const int cpx = gridDim.x >> 3;
    bid = (bid & 7) * cpx + (bid >> 3);
    const int nbx  = N >> 8;
    const int brow = (bid / nbx) << 8;
    const int bcol = (bid % nbx) << 8;

    const int srow  = tid >> 3;
    const int scole = (((tid & 7) ^ (srow & 7)) << 4) >> 1;
    const size_t aoff = (size_t)(brow + srow) * K + scole;
    const size_t boff = (size_t)(bcol + srow) * K + scole;
    const size_t rowK64 = (size_t)64 * K;
    const int wave1024 = w << 10;

    const int lo16 = (lane >> 4) << 4;
    const int swzm = (lane & 7) << 4;
    const int low0 = lo16 ^ swzm;
    const int low1 = (64 | lo16) ^ swzm;
    const int rA   = (lane & 15) << 7;
    const int rB   = ((((wc & 1) << 6) | (lane & 15)) << 7);
    const int regA = wr << 14;
    const int regB = 32768 + ((wc >> 1) << 14);

    bf16x8 a[4][2];
    bf16x8 b0[2][2];
    bf16x8 b1[2][2];
    f32x4 acc[8][4];
    #pragma unroll
    for (int m = 0; m < 8; ++m)
        #pragma unroll
        for (int n = 0; n < 4; ++n)
            acc[m][n] = (f32x4)(0.0f);

#define STAGE_A(buf, h, kt) do { \
    const u16* _s = A + aoff + (size_t)(h) * 128 * K + (size_t)(kt) * 64; \
    gload_lds16(_s,          lds + ((buf) << 16) + ((h) << 14) + wave1024); \
    gload_lds16(_s + rowK64, lds + ((buf) << 16) + ((h) << 14) + 8192 + wave1024); \
} while (0)

#define STAGE_B(buf, h, kt) do { \
    const u16* _s = Bt + boff + (size_t)(h) * 128 * K + (size_t)(kt) * 64; \
    gload_lds16(_s,          lds + ((buf) << 16) + 32768 + ((h) << 14) + wave1024); \
    gload_lds16(_s + rowK64, lds + ((buf) << 16) + 32768 + ((h) << 14) + 8192 + wave1024); \
} while (0)

#define READ_A(buf, g) do { \
    _Pragma("unroll") \
    for (int m = 0; m < 4; ++m) { \
        const int _b = ((buf) << 16) + regA + rA + ((((g) << 2) + m) << 11); \
        a[m][0] = *reinterpret_cast<const bf16x8*>(lds + _b + low0); \
        a[m][1] = *reinterpret_cast<const bf16x8*>(lds + _b + low1); \
    } \
} while (0)

#define READ_B0(buf) do { \
    _Pragma("unroll") \
    for (int n = 0; n < 2; ++n) { \
        const int _b = ((buf) << 16) + regB + rB + (n << 11); \
        b0[n][0] = *reinterpret_cast<const bf16x8*>(lds + _b + low0); \
        b0[n][1] = *reinterpret_cast<const bf16x8*>(lds + _b + low1); \
    } \
} while (0)

#define READ_B1(buf) do { \
    _Pragma("unroll") \
    for (int n = 0; n < 2; ++n) { \
        const int _b = ((buf) << 16) + regB + rB + ((n + 2) << 11); \
        b1[n][0] = *reinterpret_cast<const bf16x8*>(lds + _b + low0); \
        b1[n][1] = *reinterpret_cast<const bf16x8*>(lds + _b + low1); \
    } \
} while (0)

#define MM(bx, mb, nb) do { \
    __builtin_amdgcn_s_setprio(1); \
    _Pragma("unroll") \
    for (int m = 0; m < 4; ++m) \
        _Pragma("unroll") \
        for (int n = 0; n < 2; ++n) \
            _Pragma("unroll") \
            for (int s = 0; s < 2; ++s) \
                acc[(mb) + m][(nb) + n] = __builtin_amdgcn_mfma_f32_16x16x32_bf16( \
                    a[m][s], bx[n][s], acc[(mb) + m][(nb) + n], 0, 0, 0); \
    __builtin_amdgcn_s_setprio(0); \
} while (0)

    const int NT  = K >> 6;   // K-tiles of 64
    const int NIT = K >> 7;   // 2 K-tiles per iteration

    // ---- prologue: tile0 -> buf0 (8 loads), tile1 -> buf1 (8 loads) ----
    STAGE_A(0, 0, 0); STAGE_A(0, 1, 0); STAGE_B(0, 0, 0); STAGE_B(0, 1, 0);
    STAGE_A(1, 0, 1); STAGE_A(1, 1, 1); STAGE_B(1, 0, 1); STAGE_B(1, 1, 1);
    VMW8(); BARRIER();
    READ_A(0, 0); READ_B0(0);          // ph1 operands

    for (int it = 0; it < NIT; ++it) {
        const int tn0r = 2 * it + 2;
        const int tn1r = 2 * it + 3;
        const int tn0 = tn0r < NT ? tn0r : NT - 1;   // clamp: dead stages, last iter
        const int tn1 = tn1r < NT ? tn1r : NT - 1;

        // ph1
        BARRIER(); LGKM0();
        MM(b0, 0, 0);
        READ_B1(0);

        // ph2
        BARRIER(); LGKM0();
        STAGE_B(0, 0, tn0);            // B0 last read-issue: prev ph8
        MM(b1, 0, 2);
        READ_A(0, 1);

        // ph3
        BARRIER(); LGKM0();
        STAGE_B(0, 1, tn0);            // B1 last read-issue: ph1
        MM(b1, 4, 2);

        // ph4
        BARRIER(); LGKM0();
        STAGE_A(0, 0, tn0); STAGE_A(0, 1, tn0);  // A last read-issue: ph2
        MM(b0, 4, 0);
        VMW8();                        // drains prev-iter buf1 stages (lead 4 phases)
        READ_A(1, 0); READ_B0(1);

        // ph5
        BARRIER(); LGKM0();
        MM(b0, 0, 0);
        READ_B1(1);

        // ph6
        BARRIER(); LGKM0();
        STAGE_B(1, 0, tn1);
        MM(b1, 0, 2);
        READ_A(1, 1);

        // ph7
        BARRIER(); LGKM0();
        STAGE_B(1, 1, tn1);
        MM(b1, 4, 2);

        // ph8
        BARRIER(); LGKM0();
        STAGE_A(1, 0, tn1); STAGE_A(1, 1, tn1);
        MM(b0, 4, 0);
        VMW8();                        // drains this-iter buf0 stages (lead 4 phases)
        READ_A(0, 0); READ_B0(0);
    }

    // ---- epilogue ----
    float bb[4];
    #pragma unroll
    for (int n = 0; n < 4; ++n)
        bb[n] = bias[bcol + (wc << 6) + (n << 4) + (lane & 15)];

    const int erow0 = brow + (wr << 7) + ((lane >> 4) << 2);
    const int ecol0 = bcol + (wc << 6) + (lane & 15);

    #pragma unroll
    for (int m = 0; m < 8; ++m) {
        #pragma unroll
        for (int i = 0; i < 4; ++i) {
            const int r = erow0 + (m << 4) + i;
            #pragma unroll
            for (int n = 0; n < 4; ++n) {
                const int c = ecol0 + (n << 4);
                float v = acc[m][n][i] + bb[n];
                if (MODE == 0) {
                    v = v > 0.0f ? v : 0.0f;
                    obf[(size_t)r * N + c] = f2bf_bits(v);
                } else {
                    of32[(size_t)r * N + c] = v;
                }
            }
        }
    }
#undef STAGE_A
#undef STAGE_B
#undef READ_A
#undef READ_B0
#undef READ_B1
#undef MM
}

// ---------- launch ----------
extern "C" void kernel_launch(void* const* d_in, const int* in_sizes, int n_in,
                              void* d_out, int out_size, void* d_ws, size_t ws_size,
                              hipStream_t stream) {
    const float* x   = (const float*)d_in[0];
    const float* We1 = (const float*)d_in[1];
    const float* be1 = (const float*)d_in[2];
    const float* We2 = (const float*)d_in[3];
    const float* be2 = (const float*)d_in[4];
    const float* Wd1 = (const float*)d_in[5];
    const float* bd1 = (const float*)d_in[6];
    const float* Wd2 = (const float*)d_in[7];
    const float* bd2 = (const float*)d_in[8];
    const float* eps = (const float*)d_in[9];

    const int B = 4096, D = 4096, H = 4096, LAT = 512;

    char* ws = (char*)d_ws;
    u16* xb  = (u16*)(ws);
    u16* w1t = (u16*)(ws + 33554432);
    u16* w2t = (u16*)(ws + 67108864);
    u16* w3t = (u16*)(ws + 75497472);
    u16* w4t = (u16*)(ws + 79691776);
    u16* h   = (u16*)(ws + 113246208);
    u16* zs  = w1t;
    u16* hd  = xb;

    float* recon = (float*)d_out;
    float* mu    = recon + (size_t)B * D;
    float* lv    = mu + (size_t)B * LAT;

    hipFuncSetAttribute(reinterpret_cast<const void*>(gemm256<0>),
                        hipFuncAttributeMaxDynamicSharedMemorySize, 131072);
    hipFuncSetAttribute(reinterpret_cast<const void*>(gemm256<1>),
                        hipFuncAttributeMaxDynamicSharedMemorySize, 131072);

    cvt4<<<(B * D / 4 + 255) / 256, 256, 0, stream>>>(x, xb, B * D);
    transpose_cvt64<<<dim3(H / 64, D / 64), 256, 0, stream>>>(We1, w1t, D, H);
    transpose_cvt64<<<dim3(2 * LAT / 64, H / 64), 256, 0, stream>>>(We2, w2t, H, 2 * LAT);
    transpose_cvt64<<<dim3(H / 64, LAT / 64), 256, 0, stream>>>(Wd1, w3t, LAT, H);
    transpose_cvt64<<<dim3(D / 64, H / 64), 256, 0, stream>>>(Wd2, w4t, H, D);

    // h = relu(x @ We1 + be1)        M=B, N=H, K=D
    gemm256<0><<<(B / 256) * (H / 256), 512, 131072, stream>>>(xb, w1t, be1, h, nullptr, B, H, D);
    // z = h @ We2 + be2 -> mu, logvar  (128^2, N=1024)
    gemm_bt<2><<<(B / 128) * (2 * LAT / 128), 256, 0, stream>>>(h, w2t, be2, nullptr, mu, lv, B, 2 * LAT, H);
    // zs = mu + exp(0.5*lv)*eps
    sampler<<<(B * LAT + 255) / 256, 256, 0, stream>>>(mu, lv, eps, zs, B * LAT);
    // hd = relu(zs @ Wd1 + bd1)      M=B, N=H, K=LAT
    gemm256<0><<<(B / 256) * (H / 256), 512, 131072, stream>>>(zs, w3t, bd1, hd, nullptr, B, H, LAT);
    // recon = hd @ Wd2 + bd2         M=B, N=D, K=H
    gemm256<1><<<(B / 256) * (D / 256), 512, 131072, stream>>>(hd, w4t, bd2, nullptr, recon, B, D, H);
}